// Round 16
// baseline (149.632 us; speedup 1.0000x reference)
//
#include <hip/hip_runtime.h>
#include <cstdint>
#include <cstddef>

typedef __bf16 bf16;
typedef __bf16 bf16x4 __attribute__((ext_vector_type(4)));
typedef __bf16 bf16x8 __attribute__((ext_vector_type(8)));
typedef float  f32x4  __attribute__((ext_vector_type(4)));
typedef float  f32x16 __attribute__((ext_vector_type(16)));

#define B_  2
#define T_  2048
#define D_  1024
#define H_  16
#define HD_ 64
#define M_  (B_ * T_)   // 4096 rows

#define GLOAD_LDS(gsrc, ldst) \
    __builtin_amdgcn_global_load_lds( \
        (const __attribute__((address_space(1))) void*)(gsrc), \
        (__attribute__((address_space(3))) void*)(ldst), 16, 0, 0)

// ------- merged prologue: z<4 -> transpose+cast W_z; z==4 -> cast x -------
__global__ void prep_kernel(
    const float* __restrict__ x,  bf16* __restrict__ xb,
    const float* __restrict__ W0, bf16* __restrict__ T0,
    const float* __restrict__ W1, bf16* __restrict__ T1,
    const float* __restrict__ W2, bf16* __restrict__ T2,
    const float* __restrict__ W3, bf16* __restrict__ T3)
{
    if (blockIdx.z == 4) {
        const int linear = blockIdx.y * 32 + blockIdx.x;
        const int base = linear * 4096 + threadIdx.x * 4;
        #pragma unroll
        for (int u = 0; u < 4; ++u) {
            const int i = base + u * 1024;
            const float4 v = *reinterpret_cast<const float4*>(x + i);
            bf16x4 o = { (bf16)v.x, (bf16)v.y, (bf16)v.z, (bf16)v.w };
            *reinterpret_cast<bf16x4*>(xb + i) = o;
        }
        return;
    }
    __shared__ float tile[32][33];
    const float* W = blockIdx.z == 0 ? W0 : blockIdx.z == 1 ? W1 : blockIdx.z == 2 ? W2 : W3;
    bf16*       Wt = blockIdx.z == 0 ? T0 : blockIdx.z == 1 ? T1 : blockIdx.z == 2 ? T2 : T3;
    const int tx = threadIdx.x & 31, ty = threadIdx.x >> 5;  // 32 x 8
    const int bx = blockIdx.x * 32, by = blockIdx.y * 32;
    #pragma unroll
    for (int r = 0; r < 32; r += 8)
        tile[ty + r][tx] = W[(size_t)(by + ty + r) * D_ + bx + tx];
    __syncthreads();
    #pragma unroll
    for (int r = 0; r < 32; r += 8)
        Wt[(size_t)(bx + ty + r) * D_ + by + tx] = (bf16)tile[tx][ty + r];
}

// ======== 128x128 bf16 GEMM core: 32x32x16 MFMA, 2-phase dbuf, T2 swizzle ========
__device__ __forceinline__ void gemm_128_2ph(
    const bf16* __restrict__ A, const bf16* __restrict__ Bt,
    int m0, int n0, bf16 (*As)[128][64], bf16 (*Bs)[128][64], f32x16 acc[2][2])
{
    constexpr int K = D_;
    constexpr int NK = K / 64;
    const int tid  = threadIdx.x;
    const int wave = tid >> 6, lane = tid & 63;
    const int l5 = lane & 31, hi = lane >> 5;
    const int wr = wave >> 1, wc = wave & 1;

    const int rseg = lane >> 3;              // 0..7
    const int srcc = (lane & 7) ^ rseg;      // pre-swizzled source chunk

    auto stage = [&](int b, int k0) {
        #pragma unroll
        for (int cc = 0; cc < 4; ++cc) {
            const int c   = wave * 4 + cc;
            const int row = c * 8 + rseg;
            GLOAD_LDS(A  + (size_t)(m0 + row) * K + k0 + srcc * 8, &As[b][c * 8][0]);
            GLOAD_LDS(Bt + (size_t)(n0 + row) * K + k0 + srcc * 8, &Bs[b][c * 8][0]);
        }
    };

    stage(0, 0);
    __syncthreads();

    #pragma unroll 1
    for (int t = 0; t < NK; ++t) {
        const int cur = t & 1;
        if (t + 1 < NK) stage(cur ^ 1, (t + 1) * 64);   // prefetch next tile first

        bf16x8 af[2][4], bfr[2][4];
        #pragma unroll
        for (int mi = 0; mi < 2; ++mi)
            #pragma unroll
            for (int ks = 0; ks < 4; ++ks) {
                const int row = wr * 64 + mi * 32 + l5;
                af[mi][ks] = *reinterpret_cast<const bf16x8*>(
                    &As[cur][row][((ks * 2 + hi) ^ (row & 7)) * 8]);
            }
        #pragma unroll
        for (int nj = 0; nj < 2; ++nj)
            #pragma unroll
            for (int ks = 0; ks < 4; ++ks) {
                const int row = wc * 64 + nj * 32 + l5;
                bfr[nj][ks] = *reinterpret_cast<const bf16x8*>(
                    &Bs[cur][row][((ks * 2 + hi) ^ (row & 7)) * 8]);
            }
        __builtin_amdgcn_s_setprio(1);
        #pragma unroll
        for (int mi = 0; mi < 2; ++mi)
            #pragma unroll
            for (int nj = 0; nj < 2; ++nj)
                #pragma unroll
                for (int ks = 0; ks < 4; ++ks)
                    acc[mi][nj] = __builtin_amdgcn_mfma_f32_32x32x16_bf16(
                        af[mi][ks], bfr[nj][ks], acc[mi][nj], 0, 0, 0);
        __builtin_amdgcn_s_setprio(0);
        __syncthreads();
    }
}

// ================= fused QKV projection, 128^2 tiles, 768 blocks =================
__global__ __launch_bounds__(256, 2) void qkv128_kernel(
    const bf16* __restrict__ xb,
    const bf16* __restrict__ WqT, const float* __restrict__ bq, bf16* __restrict__ Qo,
    const bf16* __restrict__ WkT, const float* __restrict__ bk, bf16* __restrict__ Ko,
    const bf16* __restrict__ WvT, const float* __restrict__ bv, bf16* __restrict__ Vt)
{
    __shared__ bf16 As[2][128][64];   // 32 KB
    __shared__ bf16 Bs[2][128][64];   // 32 KB

    const int bid = blockIdx.x;
    const int swz = (bid & 7) * 96 + (bid >> 3);   // XCD-bijective (768 % 8 == 0)

    const bf16 *Aop, *Bop;
    const float *bias;
    bf16 *outp;
    float scale = 1.0f;
    int m0, n0, mode;
    if (swz < 512) {
        const int bm = swz & 31, bn = swz >> 5;    // bm 0..31 (tokens), bn 0..15 (Q|K)
        m0 = bm * 128;
        Aop = xb;
        if (bn < 8) { Bop = WqT; n0 = bn * 128;       bias = bq; outp = Qo;
                      scale = 0.125f * 1.44269504f; }   // fold log2e for exp2 softmax
        else        { Bop = WkT; n0 = (bn - 8) * 128; bias = bk; outp = Ko; }
        mode = 0;
    } else {
        const int v = swz - 512, bm = v & 7, bn = v >> 3;  // bm 0..7 (d), bn 0..31 (tokens)
        m0 = bm * 128; n0 = bn * 128;
        Aop = WvT; Bop = xb; bias = bv; outp = Vt; mode = 1;
    }

    f32x16 acc[2][2] = {};
    gemm_128_2ph(Aop, Bop, m0, n0, As, Bs, acc);

    const int lane = threadIdx.x & 63, wave = threadIdx.x >> 6;
    const int l5 = lane & 31, hi = lane >> 5;
    const int wr = wave >> 1, wc = wave & 1;
    if (mode == 0) {
        #pragma unroll
        for (int mi = 0; mi < 2; ++mi)
            #pragma unroll
            for (int nj = 0; nj < 2; ++nj)
                #pragma unroll
                for (int q = 0; q < 16; ++q) {
                    const int m = m0 + wr * 64 + mi * 32 + (q & 3) + 8 * (q >> 2) + 4 * hi;
                    const int n = n0 + wc * 64 + nj * 32 + l5;
                    const float val = (acc[mi][nj][q] + bias[n]) * scale;
                    const int b = m >> 11, t = m & (T_ - 1);
                    const int h = n >> 6, hd = n & 63;
                    outp[((size_t)((b * H_ + h) * T_ + t)) * HD_ + hd] = (bf16)val;
                }
    } else {
        #pragma unroll
        for (int mi = 0; mi < 2; ++mi)
            #pragma unroll
            for (int nj = 0; nj < 2; ++nj)
                #pragma unroll
                for (int q = 0; q < 16; ++q) {
                    const int d = m0 + wr * 64 + mi * 32 + (q & 3) + 8 * (q >> 2) + 4 * hi;
                    const int n = n0 + wc * 64 + nj * 32 + l5;
                    const float val = acc[mi][nj][q] + bias[d];
                    const int b = n >> 11, t = n & (T_ - 1);
                    outp[((size_t)(b * D_ + d)) * T_ + t] = (bf16)val;
                }
    }
}

// ========= out projection: BM=64 x BN=128 tiles, 512 blocks (2/CU), fp32 out =========
__global__ __launch_bounds__(256, 2) void gemm_out_kernel(
    const bf16* __restrict__ A, const bf16* __restrict__ WoT,
    const float* __restrict__ bo, float* __restrict__ Out)
{
    constexpr int K = D_;
    constexpr int NK = K / 64;
    __shared__ bf16 As[2][64][64];    // 16 KB
    __shared__ bf16 Bs[2][128][64];   // 32 KB

    const int bid = blockIdx.x;
    const int swz = (bid & 7) * 64 + (bid >> 3);   // XCD-bijective (512 % 8 == 0)
    const int m0 = (swz & 63) * 64, n0 = (swz >> 6) * 128;

    const int tid = threadIdx.x, wave = tid >> 6, lane = tid & 63;
    const int l5 = lane & 31, hi = lane >> 5;
    const int rseg = lane >> 3;
    const int srcc = (lane & 7) ^ rseg;

    auto stage = [&](int b, int k0) {
        #pragma unroll
        for (int cc = 0; cc < 2; ++cc) {       // A: 8 segs, 2/wave
            const int seg = wave * 2 + cc;
            const int row = seg * 8 + rseg;
            GLOAD_LDS(A + (size_t)(m0 + row) * K + k0 + srcc * 8, &As[b][seg * 8][0]);
        }
        #pragma unroll
        for (int cc = 0; cc < 4; ++cc) {       // B: 16 segs, 4/wave
            const int seg = wave * 4 + cc;
            const int row = seg * 8 + rseg;
            GLOAD_LDS(WoT + (size_t)(n0 + row) * K + k0 + srcc * 8, &Bs[b][seg * 8][0]);
        }
    };

    f32x16 acc[2] = {};
    stage(0, 0);
    __syncthreads();

    #pragma unroll 1
    for (int t = 0; t < NK; ++t) {
        const int cur = t & 1;
        if (t + 1 < NK) stage(cur ^ 1, (t + 1) * 64);

        bf16x8 af[2][4], bfr[4];
        #pragma unroll
        for (int mi = 0; mi < 2; ++mi)
            #pragma unroll
            for (int ks = 0; ks < 4; ++ks) {
                const int row = mi * 32 + l5;
                af[mi][ks] = *reinterpret_cast<const bf16x8*>(
                    &As[cur][row][((ks * 2 + hi) ^ (row & 7)) * 8]);
            }
        #pragma unroll
        for (int ks = 0; ks < 4; ++ks) {
            const int row = wave * 32 + l5;
            bfr[ks] = *reinterpret_cast<const bf16x8*>(
                &Bs[cur][row][((ks * 2 + hi) ^ (row & 7)) * 8]);
        }
        __builtin_amdgcn_s_setprio(1);
        #pragma unroll
        for (int mi = 0; mi < 2; ++mi)
            #pragma unroll
            for (int ks = 0; ks < 4; ++ks)
                acc[mi] = __builtin_amdgcn_mfma_f32_32x32x16_bf16(
                    af[mi][ks], bfr[ks], acc[mi], 0, 0, 0);
        __builtin_amdgcn_s_setprio(0);
        __syncthreads();
    }

    #pragma unroll
    for (int mi = 0; mi < 2; ++mi)
        #pragma unroll
        for (int q = 0; q < 16; ++q) {
            const int m = m0 + mi * 32 + (q & 3) + 8 * (q >> 2) + 4 * hi;
            const int n = n0 + wave * 32 + l5;
            Out[(size_t)m * D_ + n] = acc[mi][q] + bo[n];
        }
}

// ==== flash attention: 32x32 swapped QK^T, in-register softmax, no P LDS ====
// 256 singleton blocks x 8 waves (2 waves/SIMD): block = (bh, 256-q super-block s).
// XCD-grouped: xcd = bid&7, bh = xcd*4 + (j>>3), s = j&7. nt = 4s+4 tiles.
// Lane holds q = lane&31; P -> PV A-fragment via cvt_pk + permlane32_swap
// (guide m214 recipe operand order: swap(low-keys word, high-keys word)).
__device__ __forceinline__ bf16x8 mk8(unsigned a, unsigned b, unsigned c, unsigned d) {
    union { unsigned u[4]; bf16x8 v; } x;
    x.u[0] = a; x.u[1] = b; x.u[2] = c; x.u[3] = d;
    return x.v;
}

__global__ __launch_bounds__(512) void attn_kernel(
    const bf16* __restrict__ Q, const bf16* __restrict__ K,
    const bf16* __restrict__ Vt, bf16* __restrict__ Out)
{
    const int bid = blockIdx.x;
    const int xcd = bid & 7, j = bid >> 3;       // j 0..31
    const int bh  = xcd * 4 + (j >> 3);          // 4 bh per XCD
    const int s_  = j & 7;                       // 256-q super-block 0..7

    const int tid = threadIdx.x, wave = tid >> 6, lane = tid & 63;  // 8 waves
    const int l5 = lane & 31, hi = lane >> 5;
    const size_t kbase = (size_t)bh * T_ * HD_;   // Q,K
    const size_t vbase = (size_t)bh * HD_ * T_;   // Vt

    __shared__ bf16 Ks[2][64][64];   // 16 KB
    __shared__ bf16 Vs[2][64][64];   // 16 KB  (Vs[buf][d][key])

    auto stage = [&](int sb, int kt) {
        const int kv0 = kt * 64;
        const int rseg = lane >> 3;
        const int srcw = (lane & 7) ^ rseg;      // XOR source-chunk swizzle (involution)
        const int row  = wave * 8 + rseg;        // seg = wave (8 waves x 8 rows)
        GLOAD_LDS(K  + kbase + (size_t)(kv0 + row) * HD_ + srcw * 8, &Ks[sb][wave * 8][0]);
        GLOAD_LDS(Vt + vbase + (size_t)row * T_ + kv0 + srcw * 8,    &Vs[sb][wave * 8][0]);
    };
    auto kfrag = [&](int sb, int row, int chunk) {
        return *reinterpret_cast<const bf16x8*>(&Ks[sb][row][(chunk ^ (row & 7)) * 8]);
    };
    auto vfrag = [&](int sb, int row, int chunk) {
        return *reinterpret_cast<const bf16x8*>(&Vs[sb][row][(chunk ^ (row & 7)) * 8]);
    };

    const int q0 = s_ * 256;
    const int nt = 4 * s_ + 4;                   // 64-key tiles needed
    const int qw = wave * 32;
    const int q_abs = q0 + qw + l5;              // this lane's q row

    // Q B-fragments: col=q=lane&31, k-slice s: d = s*16 + hi*8 + i
    bf16x8 qf[4];
    {
        const bf16* qrow = Q + kbase + (size_t)q_abs * HD_;
        #pragma unroll
        for (int s = 0; s < 4; ++s)
            qf[s] = *reinterpret_cast<const bf16x8*>(qrow + s * 16 + hi * 8);
    }

    float m_s = -1e30f, l_s = 0.f;               // log2-domain state for q = q_abs
    f32x16 o0 = {}, o1 = {};                     // O[q'][d]: q' = ridx, d = l5 / 32+l5

    stage(0, 0);
    __syncthreads();

    #pragma unroll 1
    for (int t = 0; t < nt; ++t) {
        const int cur = t & 1;
        if (t + 1 < nt) stage(cur ^ 1, t + 1);   // prefetch next tile

        const int kv0 = t * 64;
        if (kv0 <= q0 + qw + 31) {               // wave-uniform activity
            // S'[key][q] = mfma(A=K, B=Q): lane holds q=l5; keys (r&3)+8(r>>2)+4hi (+32 for s1)
            f32x16 s0 = {}, s1 = {};
            __builtin_amdgcn_s_setprio(1);
            #pragma unroll
            for (int s = 0; s < 4; ++s) {
                s0 = __builtin_amdgcn_mfma_f32_32x32x16_bf16(
                    kfrag(cur, l5,      2 * s + hi), qf[s], s0, 0, 0, 0);
                s1 = __builtin_amdgcn_mfma_f32_32x32x16_bf16(
                    kfrag(cur, 32 + l5, 2 * s + hi), qf[s], s1, 0, 0, 0);
            }
            __builtin_amdgcn_s_setprio(0);
            // causal mask (diagonal region = last 4 tiles of this super-block)
            if (t >= 4 * s_) {
                #pragma unroll
                for (int r = 0; r < 16; ++r) {
                    const int ridx = (r & 3) + 8 * (r >> 2) + 4 * hi;
                    if (kv0 + ridx > q_abs)      s0[r] = -1e30f;
                    if (kv0 + 32 + ridx > q_abs) s1[r] = -1e30f;
                }
            }
            // in-register softmax: lane-local max + ONE shfl
            float mx = -1e30f;
            #pragma unroll
            for (int r = 0; r < 16; ++r) mx = fmaxf(mx, fmaxf(s0[r], s1[r]));
            mx = fmaxf(mx, __shfl_xor(mx, 32));
            if (__any(mx > m_s + 11.5416f)) {    // defer-max (8 nats in bits)
                const float mnew  = fmaxf(m_s, mx);
                const float alpha = exp2f(m_s - mnew);
                #pragma unroll
                for (int r = 0; r < 16; ++r) {
                    const float a = __shfl(alpha, (r & 3) + 8 * (r >> 2) + 4 * hi);
                    o0[r] *= a; o1[r] *= a;
                }
                l_s *= alpha;
                m_s = mnew;
            }
            float rs = 0.f;
            #pragma unroll
            for (int r = 0; r < 16; ++r) {
                s0[r] = exp2f(s0[r] - m_s); rs += s0[r];
                s1[r] = exp2f(s1[r] - m_s); rs += s1[r];
            }
            rs += __shfl_xor(rs, 32);
            l_s += rs;
            // P -> PV A-fragments: cvt_pk pairs, then permlane32_swap
            // (m214 recipe order: swap(pk(p[2i],p[2i+1]), pk(p[2i+4],p[2i+5])))
            unsigned u[8], w[8];
            #pragma unroll
            for (int i = 0; i < 8; ++i) {
                asm("v_cvt_pk_bf16_f32 %0, %1, %2" : "=v"(u[i]) : "v"(s0[2*i]), "v"(s0[2*i+1]));
                asm("v_cvt_pk_bf16_f32 %0, %1, %2" : "=v"(w[i]) : "v"(s1[2*i]), "v"(s1[2*i+1]));
            }
            asm("v_permlane32_swap_b32 %0, %1" : "+v"(u[0]), "+v"(u[2]));
            asm("v_permlane32_swap_b32 %0, %1" : "+v"(u[1]), "+v"(u[3]));
            asm("v_permlane32_swap_b32 %0, %1" : "+v"(u[4]), "+v"(u[6]));
            asm("v_permlane32_swap_b32 %0, %1" : "+v"(u[5]), "+v"(u[7]));
            asm("v_permlane32_swap_b32 %0, %1" : "+v"(w[0]), "+v"(w[2]));
            asm("v_permlane32_swap_b32 %0, %1" : "+v"(w[1]), "+v"(w[3]));
            asm("v_permlane32_swap_b32 %0, %1" : "+v"(w[4]), "+v"(w[6]));
            asm("v_permlane32_swap_b32 %0, %1" : "+v"(w[5]), "+v"(w[7]));
            const bf16x8 pf0 = mk8(u[0], u[1], u[2], u[3]);  // keys  0..15 slice
            const bf16x8 pf1 = mk8(u[4], u[5], u[6], u[7]);  // keys 16..31
            const bf16x8 pf2 = mk8(w[0], w[1], w[2], w[3]);  // keys 32..47
            const bf16x8 pf3 = mk8(w[4], w[5], w[6], w[7]);  // keys 48..63
            // O += P @ V : A row=q=l5, B col=d (l5 / 32+l5), k=key slice
            __builtin_amdgcn_s_setprio(1);
            o0 = __builtin_amdgcn_mfma_f32_32x32x16_bf16(pf0, vfrag(cur, l5,      0 + hi), o0, 0, 0, 0);
            o0 = __builtin_amdgcn_mfma_f32_32x32x16_bf16(pf1, vfrag(cur, l5,      2 + hi), o0, 0, 0, 0);
            o0 = __builtin_amdgcn_mfma_f32_32x32x16_bf16(pf2, vfrag(cur, l5,      4 + hi), o0, 0, 0, 0);
            o0 = __builtin_amdgcn_mfma_f32_32x32x16_bf16(pf3, vfrag(cur, l5,      6 + hi), o0, 0, 0, 0);
            o1 = __builtin_amdgcn_mfma_f32_32x32x16_bf16(pf0, vfrag(cur, 32 + l5, 0 + hi), o1, 0, 0, 0);
            o1 = __builtin_amdgcn_mfma_f32_32x32x16_bf16(pf1, vfrag(cur, 32 + l5, 2 + hi), o1, 0, 0, 0);
            o1 = __builtin_amdgcn_mfma_f32_32x32x16_bf16(pf2, vfrag(cur, 32 + l5, 4 + hi), o1, 0, 0, 0);
            o1 = __builtin_amdgcn_mfma_f32_32x32x16_bf16(pf3, vfrag(cur, 32 + l5, 6 + hi), o1, 0, 0, 0);
            __builtin_amdgcn_s_setprio(0);
        }
        __syncthreads();   // all reads of cur done; next tile fully staged
    }

    // normalize + store: O row q' = (r&3)+8*(r>>2)+4*hi, col d = l5 / 32+l5
    const int b = bh >> 4, h = bh & 15;
    const float linv = 1.0f / l_s;
    #pragma unroll
    for (int r = 0; r < 16; ++r) {
        const int ridx = (r & 3) + 8 * (r >> 2) + 4 * hi;
        const float li = __shfl(linv, ridx);
        const int qo = q0 + qw + ridx;
        bf16* orow = Out + ((size_t)(b * T_ + qo)) * D_ + h * HD_;
        orow[l5]      = (bf16)(o0[r] * li);
        orow[32 + l5] = (bf16)(o1[r] * li);
    }
}

// ---------------- launch ----------------
extern "C" void kernel_launch(void* const* d_in, const int* in_sizes, int n_in,
                              void* d_out, int out_size, void* d_ws, size_t ws_size,
                              hipStream_t stream) {
    const float* x  = (const float*)d_in[0];
    const float* Wq = (const float*)d_in[1];
    const float* bq = (const float*)d_in[2];
    const float* Wk = (const float*)d_in[3];
    const float* bk = (const float*)d_in[4];
    const float* Wv = (const float*)d_in[5];
    const float* bv = (const float*)d_in[6];
    const float* Wo = (const float*)d_in[7];
    const float* bo = (const float*)d_in[8];
    float* out = (float*)d_out;

    char* ws = (char*)d_ws;
    bf16* xb   = (bf16*)(ws);                         // 8 MB  [4096][1024]
    bf16* WqT  = (bf16*)(ws + ( 8u << 20));           // 2 MB  [1024][1024]
    bf16* WkT  = (bf16*)(ws + (10u << 20));
    bf16* WvT  = (bf16*)(ws + (12u << 20));
    bf16* WoT  = (bf16*)(ws + (14u << 20));
    bf16* Qb   = (bf16*)(ws + (16u << 20));           // 8 MB  [32][2048][64]
    bf16* Kb   = (bf16*)(ws + (24u << 20));
    bf16* Vtb  = (bf16*)(ws + (32u << 20));           // 8 MB  [32][64][2048]
    bf16* attn = (bf16*)(ws + (40u << 20));           // 8 MB  [4096][1024]

    prep_kernel<<<dim3(32, 32, 5), 256, 0, stream>>>(
        x, xb, Wq, WqT, Wk, WkT, Wv, WvT, Wo, WoT);

    qkv128_kernel<<<768, 256, 0, stream>>>(xb, WqT, bq, Qb, WkT, bk, Kb, WvT, bv, Vtb);

    attn_kernel<<<256, 512, 0, stream>>>(Qb, Kb, Vtb, attn);

    gemm_out_kernel<<<512, 256, 0, stream>>>(attn, WoT, bo, out);
}

// Round 17
// 130.357 us; speedup vs baseline: 1.1479x; 1.1479x over previous
//
#include <hip/hip_runtime.h>
#include <cstdint>
#include <cstddef>

typedef __bf16 bf16;
typedef __bf16 bf16x4 __attribute__((ext_vector_type(4)));
typedef __bf16 bf16x8 __attribute__((ext_vector_type(8)));
typedef float  f32x4  __attribute__((ext_vector_type(4)));
typedef float  f32x16 __attribute__((ext_vector_type(16)));

#define B_  2
#define T_  2048
#define D_  1024
#define H_  16
#define HD_ 64
#define M_  (B_ * T_)   // 4096 rows
#define NQB 32          // T_/64 q-blocks

#define GLOAD_LDS(gsrc, ldst) \
    __builtin_amdgcn_global_load_lds( \
        (const __attribute__((address_space(1))) void*)(gsrc), \
        (__attribute__((address_space(3))) void*)(ldst), 16, 0, 0)

// ------- merged prologue: z<4 -> transpose+cast W_z; z==4 -> cast x -------
__global__ void prep_kernel(
    const float* __restrict__ x,  bf16* __restrict__ xb,
    const float* __restrict__ W0, bf16* __restrict__ T0,
    const float* __restrict__ W1, bf16* __restrict__ T1,
    const float* __restrict__ W2, bf16* __restrict__ T2,
    const float* __restrict__ W3, bf16* __restrict__ T3)
{
    if (blockIdx.z == 4) {
        const int linear = blockIdx.y * 32 + blockIdx.x;
        const int base = linear * 4096 + threadIdx.x * 4;
        #pragma unroll
        for (int u = 0; u < 4; ++u) {
            const int i = base + u * 1024;
            const float4 v = *reinterpret_cast<const float4*>(x + i);
            bf16x4 o = { (bf16)v.x, (bf16)v.y, (bf16)v.z, (bf16)v.w };
            *reinterpret_cast<bf16x4*>(xb + i) = o;
        }
        return;
    }
    __shared__ float tile[32][33];
    const float* W = blockIdx.z == 0 ? W0 : blockIdx.z == 1 ? W1 : blockIdx.z == 2 ? W2 : W3;
    bf16*       Wt = blockIdx.z == 0 ? T0 : blockIdx.z == 1 ? T1 : blockIdx.z == 2 ? T2 : T3;
    const int tx = threadIdx.x & 31, ty = threadIdx.x >> 5;  // 32 x 8
    const int bx = blockIdx.x * 32, by = blockIdx.y * 32;
    #pragma unroll
    for (int r = 0; r < 32; r += 8)
        tile[ty + r][tx] = W[(size_t)(by + ty + r) * D_ + bx + tx];
    __syncthreads();
    #pragma unroll
    for (int r = 0; r < 32; r += 8)
        Wt[(size_t)(bx + ty + r) * D_ + by + tx] = (bf16)tile[tx][ty + r];
}

// ======== 128x128 bf16 GEMM core: 32x32x16 MFMA, 2-phase dbuf, T2 swizzle ========
__device__ __forceinline__ void gemm_128_2ph(
    const bf16* __restrict__ A, const bf16* __restrict__ Bt,
    int m0, int n0, bf16 (*As)[128][64], bf16 (*Bs)[128][64], f32x16 acc[2][2])
{
    constexpr int K = D_;
    constexpr int NK = K / 64;
    const int tid  = threadIdx.x;
    const int wave = tid >> 6, lane = tid & 63;
    const int l5 = lane & 31, hi = lane >> 5;
    const int wr = wave >> 1, wc = wave & 1;

    const int rseg = lane >> 3;              // 0..7
    const int srcc = (lane & 7) ^ rseg;      // pre-swizzled source chunk

    auto stage = [&](int b, int k0) {
        #pragma unroll
        for (int cc = 0; cc < 4; ++cc) {
            const int c   = wave * 4 + cc;
            const int row = c * 8 + rseg;
            GLOAD_LDS(A  + (size_t)(m0 + row) * K + k0 + srcc * 8, &As[b][c * 8][0]);
            GLOAD_LDS(Bt + (size_t)(n0 + row) * K + k0 + srcc * 8, &Bs[b][c * 8][0]);
        }
    };

    stage(0, 0);
    __syncthreads();

    #pragma unroll 1
    for (int t = 0; t < NK; ++t) {
        const int cur = t & 1;
        if (t + 1 < NK) stage(cur ^ 1, (t + 1) * 64);   // prefetch next tile first

        bf16x8 af[2][4], bfr[2][4];
        #pragma unroll
        for (int mi = 0; mi < 2; ++mi)
            #pragma unroll
            for (int ks = 0; ks < 4; ++ks) {
                const int row = wr * 64 + mi * 32 + l5;
                af[mi][ks] = *reinterpret_cast<const bf16x8*>(
                    &As[cur][row][((ks * 2 + hi) ^ (row & 7)) * 8]);
            }
        #pragma unroll
        for (int nj = 0; nj < 2; ++nj)
            #pragma unroll
            for (int ks = 0; ks < 4; ++ks) {
                const int row = wc * 64 + nj * 32 + l5;
                bfr[nj][ks] = *reinterpret_cast<const bf16x8*>(
                    &Bs[cur][row][((ks * 2 + hi) ^ (row & 7)) * 8]);
            }
        __builtin_amdgcn_s_setprio(1);
        #pragma unroll
        for (int mi = 0; mi < 2; ++mi)
            #pragma unroll
            for (int nj = 0; nj < 2; ++nj)
                #pragma unroll
                for (int ks = 0; ks < 4; ++ks)
                    acc[mi][nj] = __builtin_amdgcn_mfma_f32_32x32x16_bf16(
                        af[mi][ks], bfr[nj][ks], acc[mi][nj], 0, 0, 0);
        __builtin_amdgcn_s_setprio(0);
        __syncthreads();
    }
}

// ================= fused QKV projection, 128^2 tiles, 768 blocks =================
__global__ __launch_bounds__(256, 2) void qkv128_kernel(
    const bf16* __restrict__ xb,
    const bf16* __restrict__ WqT, const float* __restrict__ bq, bf16* __restrict__ Qo,
    const bf16* __restrict__ WkT, const float* __restrict__ bk, bf16* __restrict__ Ko,
    const bf16* __restrict__ WvT, const float* __restrict__ bv, bf16* __restrict__ Vt)
{
    __shared__ bf16 As[2][128][64];   // 32 KB
    __shared__ bf16 Bs[2][128][64];   // 32 KB

    const int bid = blockIdx.x;
    const int swz = (bid & 7) * 96 + (bid >> 3);   // XCD-bijective (768 % 8 == 0)

    const bf16 *Aop, *Bop;
    const float *bias;
    bf16 *outp;
    float scale = 1.0f;
    int m0, n0, mode;
    if (swz < 512) {
        const int bm = swz & 31, bn = swz >> 5;    // bm 0..31 (tokens), bn 0..15 (Q|K)
        m0 = bm * 128;
        Aop = xb;
        if (bn < 8) { Bop = WqT; n0 = bn * 128;       bias = bq; outp = Qo;
                      scale = 0.125f * 1.44269504f; }   // fold log2e for exp2 softmax
        else        { Bop = WkT; n0 = (bn - 8) * 128; bias = bk; outp = Ko; }
        mode = 0;
    } else {
        const int v = swz - 512, bm = v & 7, bn = v >> 3;  // bm 0..7 (d), bn 0..31 (tokens)
        m0 = bm * 128; n0 = bn * 128;
        Aop = WvT; Bop = xb; bias = bv; outp = Vt; mode = 1;
    }

    f32x16 acc[2][2] = {};
    gemm_128_2ph(Aop, Bop, m0, n0, As, Bs, acc);

    const int lane = threadIdx.x & 63, wave = threadIdx.x >> 6;
    const int l5 = lane & 31, hi = lane >> 5;
    const int wr = wave >> 1, wc = wave & 1;
    if (mode == 0) {
        #pragma unroll
        for (int mi = 0; mi < 2; ++mi)
            #pragma unroll
            for (int nj = 0; nj < 2; ++nj)
                #pragma unroll
                for (int q = 0; q < 16; ++q) {
                    const int m = m0 + wr * 64 + mi * 32 + (q & 3) + 8 * (q >> 2) + 4 * hi;
                    const int n = n0 + wc * 64 + nj * 32 + l5;
                    const float val = (acc[mi][nj][q] + bias[n]) * scale;
                    const int b = m >> 11, t = m & (T_ - 1);
                    const int h = n >> 6, hd = n & 63;
                    outp[((size_t)((b * H_ + h) * T_ + t)) * HD_ + hd] = (bf16)val;
                }
    } else {
        #pragma unroll
        for (int mi = 0; mi < 2; ++mi)
            #pragma unroll
            for (int nj = 0; nj < 2; ++nj)
                #pragma unroll
                for (int q = 0; q < 16; ++q) {
                    const int d = m0 + wr * 64 + mi * 32 + (q & 3) + 8 * (q >> 2) + 4 * hi;
                    const int n = n0 + wc * 64 + nj * 32 + l5;
                    const float val = acc[mi][nj][q] + bias[d];
                    const int b = n >> 11, t = n & (T_ - 1);
                    outp[((size_t)(b * D_ + d)) * T_ + t] = (bf16)val;
                }
    }
}

// ========= out projection: BM=64 x BN=128 tiles, 512 blocks (2/CU), fp32 out =========
__global__ __launch_bounds__(256, 2) void gemm_out_kernel(
    const bf16* __restrict__ A, const bf16* __restrict__ WoT,
    const float* __restrict__ bo, float* __restrict__ Out)
{
    constexpr int K = D_;
    constexpr int NK = K / 64;
    __shared__ bf16 As[2][64][64];    // 16 KB
    __shared__ bf16 Bs[2][128][64];   // 32 KB

    const int bid = blockIdx.x;
    const int swz = (bid & 7) * 64 + (bid >> 3);   // XCD-bijective (512 % 8 == 0)
    const int m0 = (swz & 63) * 64, n0 = (swz >> 6) * 128;

    const int tid = threadIdx.x, wave = tid >> 6, lane = tid & 63;
    const int l5 = lane & 31, hi = lane >> 5;
    const int rseg = lane >> 3;
    const int srcc = (lane & 7) ^ rseg;

    auto stage = [&](int b, int k0) {
        #pragma unroll
        for (int cc = 0; cc < 2; ++cc) {       // A: 8 segs, 2/wave
            const int seg = wave * 2 + cc;
            const int row = seg * 8 + rseg;
            GLOAD_LDS(A + (size_t)(m0 + row) * K + k0 + srcc * 8, &As[b][seg * 8][0]);
        }
        #pragma unroll
        for (int cc = 0; cc < 4; ++cc) {       // B: 16 segs, 4/wave
            const int seg = wave * 4 + cc;
            const int row = seg * 8 + rseg;
            GLOAD_LDS(WoT + (size_t)(n0 + row) * K + k0 + srcc * 8, &Bs[b][seg * 8][0]);
        }
    };

    f32x16 acc[2] = {};
    stage(0, 0);
    __syncthreads();

    #pragma unroll 1
    for (int t = 0; t < NK; ++t) {
        const int cur = t & 1;
        if (t + 1 < NK) stage(cur ^ 1, (t + 1) * 64);

        bf16x8 af[2][4], bfr[4];
        #pragma unroll
        for (int mi = 0; mi < 2; ++mi)
            #pragma unroll
            for (int ks = 0; ks < 4; ++ks) {
                const int row = mi * 32 + l5;
                af[mi][ks] = *reinterpret_cast<const bf16x8*>(
                    &As[cur][row][((ks * 2 + hi) ^ (row & 7)) * 8]);
            }
        #pragma unroll
        for (int ks = 0; ks < 4; ++ks) {
            const int row = wave * 32 + l5;
            bfr[ks] = *reinterpret_cast<const bf16x8*>(
                &Bs[cur][row][((ks * 2 + hi) ^ (row & 7)) * 8]);
        }
        __builtin_amdgcn_s_setprio(1);
        #pragma unroll
        for (int mi = 0; mi < 2; ++mi)
            #pragma unroll
            for (int ks = 0; ks < 4; ++ks)
                acc[mi] = __builtin_amdgcn_mfma_f32_32x32x16_bf16(
                    af[mi][ks], bfr[ks], acc[mi], 0, 0, 0);
        __builtin_amdgcn_s_setprio(0);
        __syncthreads();
    }

    #pragma unroll
    for (int mi = 0; mi < 2; ++mi)
        #pragma unroll
        for (int q = 0; q < 16; ++q) {
            const int m = m0 + mi * 32 + (q & 3) + 8 * (q >> 2) + 4 * hi;
            const int n = n0 + wave * 32 + l5;
            Out[(size_t)m * D_ + n] = acc[mi][q] + bo[n];
        }
}

// ======= flash attention: QBLK=64, 4 waves, 512 paired blocks (2/CU), XCD-grouped =======
// Block handles q-blocks pr and 31-pr sequentially (34 staged tiles, uniform).
// Decode: xcd = bid&7, bh = xcd*4 + (bid>>3)/16, pr = (bid>>3)%16.
// Softmax in log2 domain (Q pre-scaled by 0.125*log2e); p = exp2(s - m).
__global__ __launch_bounds__(256) void attn_kernel(
    const bf16* __restrict__ Q, const bf16* __restrict__ K,
    const bf16* __restrict__ Vt, bf16* __restrict__ Out)
{
    const int bid = blockIdx.x;
    const int xcd = bid & 7, j = bid >> 3;       // j 0..63
    const int bh  = xcd * 4 + (j >> 4);          // 4 bh per XCD
    const int pr  = j & 15;                      // pair index 0..15

    const int tid = threadIdx.x, wave = tid >> 6, lane = tid & 63;  // 4 waves
    const int lr = lane & 15, lg = lane >> 4;
    const size_t kbase = (size_t)bh * T_ * HD_;   // Q,K
    const size_t vbase = (size_t)bh * HD_ * T_;   // Vt

    __shared__ bf16 Ks[2][64][64];   // 16 KB
    __shared__ bf16 Vs[2][64][64];   // 16 KB  (Vs[buf][d][key])
    __shared__ bf16 Ps[4][16][72];   // 9 KB   per-wave P[q][key], padded

    auto stage = [&](int sb, int kt) {
        const int kv0 = kt * 64;
        const int rseg = lane >> 3;
        const int srcw = (lane & 7) ^ rseg;      // XOR source-chunk swizzle (involution)
        #pragma unroll
        for (int cc = 0; cc < 2; ++cc) {
            const int seg = wave * 2 + cc;       // 0..7
            const int row = seg * 8 + rseg;      // 0..63
            GLOAD_LDS(K  + kbase + (size_t)(kv0 + row) * HD_ + srcw * 8, &Ks[sb][seg * 8][0]);
            GLOAD_LDS(Vt + vbase + (size_t)row * T_ + kv0 + srcw * 8,    &Vs[sb][seg * 8][0]);
        }
    };
    auto kfrag = [&](int sb, int row, int chunk) {
        return *reinterpret_cast<const bf16x8*>(&Ks[sb][row][(chunk ^ (row & 7)) * 8]);
    };
    auto vfrag = [&](int sb, int row, int chunk) {
        return *reinterpret_cast<const bf16x8*>(&Vs[sb][row][(chunk ^ (row & 7)) * 8]);
    };

    #pragma unroll 1
    for (int half = 0; half < 2; ++half) {
        const int qb = half == 0 ? pr : (NQB - 1 - pr);
        const int q0 = qb * 64;
        const int nt = qb + 1;                   // tiles 0..qb (all active)
        const int qw = wave * 16;

        // Q fragments for this wave's 16 rows (B-operand: col=lane&15 -> q=lr)
        bf16x8 qf[2];
        {
            const bf16* qrow = Q + kbase + (size_t)(q0 + qw + lr) * HD_;
            qf[0] = *reinterpret_cast<const bf16x8*>(qrow + lg * 8);
            qf[1] = *reinterpret_cast<const bf16x8*>(qrow + 32 + lg * 8);
        }

        float m_s = -1e30f, l_s = 0.f;           // log2-domain state for q = q0+qw+lr
        f32x4 o_acc[4] = {};                     // O[q=qw+lg*4+r][d=nd*16+lr]

        stage(0, 0);
        __syncthreads();

        #pragma unroll 1
        for (int t = 0; t < nt; ++t) {
            const int cur = t & 1;
            if (t + 1 < nt) stage(cur ^ 1, t + 1);   // prefetch next tile

            const int kv0 = t * 64;
            // S'[key][q]: key = kv0 + n16*16 + lg*4 + r, q = q0 + qw + lr
            f32x4 s[4] = {};
            __builtin_amdgcn_s_setprio(1);
            #pragma unroll
            for (int n16 = 0; n16 < 4; ++n16)
                #pragma unroll
                for (int kk = 0; kk < 2; ++kk)
                    s[n16] = __builtin_amdgcn_mfma_f32_16x16x32_bf16(
                        kfrag(cur, n16 * 16 + lr, kk * 4 + lg), qf[kk], s[n16], 0, 0, 0);
            __builtin_amdgcn_s_setprio(0);
            if (t == qb) {                       // causal mask on diagonal tile
                #pragma unroll
                for (int n16 = 0; n16 < 4; ++n16)
                    #pragma unroll
                    for (int r = 0; r < 4; ++r)
                        if (kv0 + n16 * 16 + lg * 4 + r > q0 + qw + lr)
                            s[n16][r] = -1e30f;
            }
            // online softmax, log2 domain, defer-max (8 nats = 11.54 bits)
            float mx = s[0][0];
            #pragma unroll
            for (int n16 = 0; n16 < 4; ++n16)
                #pragma unroll
                for (int r = 0; r < 4; ++r)
                    mx = fmaxf(mx, s[n16][r]);
            mx = fmaxf(mx, __shfl_xor(mx, 16));
            mx = fmaxf(mx, __shfl_xor(mx, 32));
            if (__any(mx > m_s + 11.5416f)) {
                const float mnew  = fmaxf(m_s, mx);
                const float alpha = exp2f(m_s - mnew);
                #pragma unroll
                for (int r = 0; r < 4; ++r) {
                    const float a = __shfl(alpha, lg * 4 + r);
                    #pragma unroll
                    for (int nd = 0; nd < 4; ++nd) o_acc[nd][r] *= a;
                }
                l_s *= alpha;
                m_s = mnew;
            }
            float rs = 0.f;
            #pragma unroll
            for (int n16 = 0; n16 < 4; ++n16) {
                bf16x4 pw;
                #pragma unroll
                for (int r = 0; r < 4; ++r) {
                    const float p = exp2f(s[n16][r] - m_s);   // bounded by 2^11.54
                    rs += p;
                    pw[r] = (bf16)p;
                }
                *reinterpret_cast<bf16x4*>(&Ps[wave][lr][n16 * 16 + lg * 4]) = pw;
            }
            rs += __shfl_xor(rs, 16);
            rs += __shfl_xor(rs, 32);
            l_s += rs;
            // O += P @ V
            __builtin_amdgcn_s_setprio(1);
            #pragma unroll
            for (int ks = 0; ks < 2; ++ks) {
                const bf16x8 pa = *reinterpret_cast<const bf16x8*>(&Ps[wave][lr][ks * 32 + lg * 8]);
                #pragma unroll
                for (int nd = 0; nd < 4; ++nd)
                    o_acc[nd] = __builtin_amdgcn_mfma_f32_16x16x32_bf16(
                        pa, vfrag(cur, nd * 16 + lr, ks * 4 + lg), o_acc[nd], 0, 0, 0);
            }
            __builtin_amdgcn_s_setprio(0);
            __syncthreads();   // all reads of cur done; next tile fully staged
        }

        // normalize + store to [b*T+t][h*64+d]
        const int b = bh >> 4, h = bh & 15;
        const float linv = 1.0f / l_s;
        #pragma unroll
        for (int r = 0; r < 4; ++r) {
            const float li = __shfl(linv, lg * 4 + r);
            const int q = q0 + qw + lg * 4 + r;
            #pragma unroll
            for (int nd = 0; nd < 4; ++nd) {
                const int d = nd * 16 + lr;
                Out[((size_t)(b * T_ + q)) * D_ + h * HD_ + d] = (bf16)(o_acc[nd][r] * li);
            }
        }
    }
}

// ---------------- launch ----------------
extern "C" void kernel_launch(void* const* d_in, const int* in_sizes, int n_in,
                              void* d_out, int out_size, void* d_ws, size_t ws_size,
                              hipStream_t stream) {
    const float* x  = (const float*)d_in[0];
    const float* Wq = (const float*)d_in[1];
    const float* bq = (const float*)d_in[2];
    const float* Wk = (const float*)d_in[3];
    const float* bk = (const float*)d_in[4];
    const float* Wv = (const float*)d_in[5];
    const float* bv = (const float*)d_in[6];
    const float* Wo = (const float*)d_in[7];
    const float* bo = (const float*)d_in[8];
    float* out = (float*)d_out;

    char* ws = (char*)d_ws;
    bf16* xb   = (bf16*)(ws);                         // 8 MB  [4096][1024]
    bf16* WqT  = (bf16*)(ws + ( 8u << 20));           // 2 MB  [1024][1024]
    bf16* WkT  = (bf16*)(ws + (10u << 20));
    bf16* WvT  = (bf16*)(ws + (12u << 20));
    bf16* WoT  = (bf16*)(ws + (14u << 20));
    bf16* Qb   = (bf16*)(ws + (16u << 20));           // 8 MB  [32][2048][64]
    bf16* Kb   = (bf16*)(ws + (24u << 20));
    bf16* Vtb  = (bf16*)(ws + (32u << 20));           // 8 MB  [32][64][2048]
    bf16* attn = (bf16*)(ws + (40u << 20));           // 8 MB  [4096][1024]

    prep_kernel<<<dim3(32, 32, 5), 256, 0, stream>>>(
        x, xb, Wq, WqT, Wk, WkT, Wv, WvT, Wo, WoT);

    qkv128_kernel<<<768, 256, 0, stream>>>(xb, WqT, bq, Qb, WkT, bk, Kb, WvT, bv, Vtb);

    attn_kernel<<<512, 256, 0, stream>>>(Qb, Kb, Vtb, attn);

    gemm_out_kernel<<<512, 256, 0, stream>>>(attn, WoT, bo, out);
}

// Round 18
// 123.692 us; speedup vs baseline: 1.2097x; 1.0539x over previous
//
#include <hip/hip_runtime.h>
#include <cstdint>
#include <cstddef>

typedef __bf16 bf16;
typedef __bf16 bf16x4 __attribute__((ext_vector_type(4)));
typedef __bf16 bf16x8 __attribute__((ext_vector_type(8)));
typedef float  f32x4  __attribute__((ext_vector_type(4)));
typedef float  f32x16 __attribute__((ext_vector_type(16)));

#define B_  2
#define T_  2048
#define D_  1024
#define H_  16
#define HD_ 64
#define M_  (B_ * T_)   // 4096 rows
#define NQB 32          // T_/64 q-blocks

#define GLOAD_LDS(gsrc, ldst) \
    __builtin_amdgcn_global_load_lds( \
        (const __attribute__((address_space(1))) void*)(gsrc), \
        (__attribute__((address_space(3))) void*)(ldst), 16, 0, 0)

// fast 2^x: single v_exp_f32 (ISA: D = 2^S0), no libm range handling
__device__ __forceinline__ float exp2_fast(float x) {
    float r;
    asm("v_exp_f32 %0, %1" : "=v"(r) : "v"(x));
    return r;
}

// ------- merged prologue: z<4 -> transpose+cast W_z; z==4 -> cast x -------
__global__ void prep_kernel(
    const float* __restrict__ x,  bf16* __restrict__ xb,
    const float* __restrict__ W0, bf16* __restrict__ T0,
    const float* __restrict__ W1, bf16* __restrict__ T1,
    const float* __restrict__ W2, bf16* __restrict__ T2,
    const float* __restrict__ W3, bf16* __restrict__ T3)
{
    if (blockIdx.z == 4) {
        const int linear = blockIdx.y * 32 + blockIdx.x;
        const int base = linear * 4096 + threadIdx.x * 4;
        #pragma unroll
        for (int u = 0; u < 4; ++u) {
            const int i = base + u * 1024;
            const float4 v = *reinterpret_cast<const float4*>(x + i);
            bf16x4 o = { (bf16)v.x, (bf16)v.y, (bf16)v.z, (bf16)v.w };
            *reinterpret_cast<bf16x4*>(xb + i) = o;
        }
        return;
    }
    __shared__ float tile[32][33];
    const float* W = blockIdx.z == 0 ? W0 : blockIdx.z == 1 ? W1 : blockIdx.z == 2 ? W2 : W3;
    bf16*       Wt = blockIdx.z == 0 ? T0 : blockIdx.z == 1 ? T1 : blockIdx.z == 2 ? T2 : T3;
    const int tx = threadIdx.x & 31, ty = threadIdx.x >> 5;  // 32 x 8
    const int bx = blockIdx.x * 32, by = blockIdx.y * 32;
    #pragma unroll
    for (int r = 0; r < 32; r += 8)
        tile[ty + r][tx] = W[(size_t)(by + ty + r) * D_ + bx + tx];
    __syncthreads();
    #pragma unroll
    for (int r = 0; r < 32; r += 8)
        Wt[(size_t)(bx + ty + r) * D_ + by + tx] = (bf16)tile[tx][ty + r];
}

// ======== 128x128 bf16 GEMM core: 32x32x16 MFMA, 2-phase dbuf, T2 swizzle ========
__device__ __forceinline__ void gemm_128_2ph(
    const bf16* __restrict__ A, const bf16* __restrict__ Bt,
    int m0, int n0, bf16 (*As)[128][64], bf16 (*Bs)[128][64], f32x16 acc[2][2])
{
    constexpr int K = D_;
    constexpr int NK = K / 64;
    const int tid  = threadIdx.x;
    const int wave = tid >> 6, lane = tid & 63;
    const int l5 = lane & 31, hi = lane >> 5;
    const int wr = wave >> 1, wc = wave & 1;

    const int rseg = lane >> 3;              // 0..7
    const int srcc = (lane & 7) ^ rseg;      // pre-swizzled source chunk

    auto stage = [&](int b, int k0) {
        #pragma unroll
        for (int cc = 0; cc < 4; ++cc) {
            const int c   = wave * 4 + cc;
            const int row = c * 8 + rseg;
            GLOAD_LDS(A  + (size_t)(m0 + row) * K + k0 + srcc * 8, &As[b][c * 8][0]);
            GLOAD_LDS(Bt + (size_t)(n0 + row) * K + k0 + srcc * 8, &Bs[b][c * 8][0]);
        }
    };

    stage(0, 0);
    __syncthreads();

    #pragma unroll 1
    for (int t = 0; t < NK; ++t) {
        const int cur = t & 1;
        if (t + 1 < NK) stage(cur ^ 1, (t + 1) * 64);   // prefetch next tile first

        bf16x8 af[2][4], bfr[2][4];
        #pragma unroll
        for (int mi = 0; mi < 2; ++mi)
            #pragma unroll
            for (int ks = 0; ks < 4; ++ks) {
                const int row = wr * 64 + mi * 32 + l5;
                af[mi][ks] = *reinterpret_cast<const bf16x8*>(
                    &As[cur][row][((ks * 2 + hi) ^ (row & 7)) * 8]);
            }
        #pragma unroll
        for (int nj = 0; nj < 2; ++nj)
            #pragma unroll
            for (int ks = 0; ks < 4; ++ks) {
                const int row = wc * 64 + nj * 32 + l5;
                bfr[nj][ks] = *reinterpret_cast<const bf16x8*>(
                    &Bs[cur][row][((ks * 2 + hi) ^ (row & 7)) * 8]);
            }
        __builtin_amdgcn_s_setprio(1);
        #pragma unroll
        for (int mi = 0; mi < 2; ++mi)
            #pragma unroll
            for (int nj = 0; nj < 2; ++nj)
                #pragma unroll
                for (int ks = 0; ks < 4; ++ks)
                    acc[mi][nj] = __builtin_amdgcn_mfma_f32_32x32x16_bf16(
                        af[mi][ks], bfr[nj][ks], acc[mi][nj], 0, 0, 0);
        __builtin_amdgcn_s_setprio(0);
        __syncthreads();
    }
}

// ================= fused QKV projection, 128^2 tiles, 768 blocks =================
__global__ __launch_bounds__(256, 2) void qkv128_kernel(
    const bf16* __restrict__ xb,
    const bf16* __restrict__ WqT, const float* __restrict__ bq, bf16* __restrict__ Qo,
    const bf16* __restrict__ WkT, const float* __restrict__ bk, bf16* __restrict__ Ko,
    const bf16* __restrict__ WvT, const float* __restrict__ bv, bf16* __restrict__ Vt)
{
    __shared__ bf16 As[2][128][64];   // 32 KB
    __shared__ bf16 Bs[2][128][64];   // 32 KB

    const int bid = blockIdx.x;
    const int swz = (bid & 7) * 96 + (bid >> 3);   // XCD-bijective (768 % 8 == 0)

    const bf16 *Aop, *Bop;
    const float *bias;
    bf16 *outp;
    float scale = 1.0f;
    int m0, n0, mode;
    if (swz < 512) {
        const int bm = swz & 31, bn = swz >> 5;    // bm 0..31 (tokens), bn 0..15 (Q|K)
        m0 = bm * 128;
        Aop = xb;
        if (bn < 8) { Bop = WqT; n0 = bn * 128;       bias = bq; outp = Qo;
                      scale = 0.125f * 1.44269504f; }   // fold log2e for exp2 softmax
        else        { Bop = WkT; n0 = (bn - 8) * 128; bias = bk; outp = Ko; }
        mode = 0;
    } else {
        const int v = swz - 512, bm = v & 7, bn = v >> 3;  // bm 0..7 (d), bn 0..31 (tokens)
        m0 = bm * 128; n0 = bn * 128;
        Aop = WvT; Bop = xb; bias = bv; outp = Vt; mode = 1;
    }

    f32x16 acc[2][2] = {};
    gemm_128_2ph(Aop, Bop, m0, n0, As, Bs, acc);

    const int lane = threadIdx.x & 63, wave = threadIdx.x >> 6;
    const int l5 = lane & 31, hi = lane >> 5;
    const int wr = wave >> 1, wc = wave & 1;
    if (mode == 0) {
        #pragma unroll
        for (int mi = 0; mi < 2; ++mi)
            #pragma unroll
            for (int nj = 0; nj < 2; ++nj)
                #pragma unroll
                for (int q = 0; q < 16; ++q) {
                    const int m = m0 + wr * 64 + mi * 32 + (q & 3) + 8 * (q >> 2) + 4 * hi;
                    const int n = n0 + wc * 64 + nj * 32 + l5;
                    const float val = (acc[mi][nj][q] + bias[n]) * scale;
                    const int b = m >> 11, t = m & (T_ - 1);
                    const int h = n >> 6, hd = n & 63;
                    outp[((size_t)((b * H_ + h) * T_ + t)) * HD_ + hd] = (bf16)val;
                }
    } else {
        #pragma unroll
        for (int mi = 0; mi < 2; ++mi)
            #pragma unroll
            for (int nj = 0; nj < 2; ++nj)
                #pragma unroll
                for (int q = 0; q < 16; ++q) {
                    const int d = m0 + wr * 64 + mi * 32 + (q & 3) + 8 * (q >> 2) + 4 * hi;
                    const int n = n0 + wc * 64 + nj * 32 + l5;
                    const float val = acc[mi][nj][q] + bias[d];
                    const int b = n >> 11, t = n & (T_ - 1);
                    outp[((size_t)(b * D_ + d)) * T_ + t] = (bf16)val;
                }
    }
}

// ========= out projection: BM=64 x BN=128 tiles, 512 blocks (2/CU), fp32 out =========
__global__ __launch_bounds__(256, 2) void gemm_out_kernel(
    const bf16* __restrict__ A, const bf16* __restrict__ WoT,
    const float* __restrict__ bo, float* __restrict__ Out)
{
    constexpr int K = D_;
    constexpr int NK = K / 64;
    __shared__ bf16 As[2][64][64];    // 16 KB
    __shared__ bf16 Bs[2][128][64];   // 32 KB

    const int bid = blockIdx.x;
    const int swz = (bid & 7) * 64 + (bid >> 3);   // XCD-bijective (512 % 8 == 0)
    const int m0 = (swz & 63) * 64, n0 = (swz >> 6) * 128;

    const int tid = threadIdx.x, wave = tid >> 6, lane = tid & 63;
    const int l5 = lane & 31, hi = lane >> 5;
    const int rseg = lane >> 3;
    const int srcc = (lane & 7) ^ rseg;

    auto stage = [&](int b, int k0) {
        #pragma unroll
        for (int cc = 0; cc < 2; ++cc) {       // A: 8 segs, 2/wave
            const int seg = wave * 2 + cc;
            const int row = seg * 8 + rseg;
            GLOAD_LDS(A + (size_t)(m0 + row) * K + k0 + srcc * 8, &As[b][seg * 8][0]);
        }
        #pragma unroll
        for (int cc = 0; cc < 4; ++cc) {       // B: 16 segs, 4/wave
            const int seg = wave * 4 + cc;
            const int row = seg * 8 + rseg;
            GLOAD_LDS(WoT + (size_t)(n0 + row) * K + k0 + srcc * 8, &Bs[b][seg * 8][0]);
        }
    };

    f32x16 acc[2] = {};
    stage(0, 0);
    __syncthreads();

    #pragma unroll 1
    for (int t = 0; t < NK; ++t) {
        const int cur = t & 1;
        if (t + 1 < NK) stage(cur ^ 1, (t + 1) * 64);

        bf16x8 af[2][4], bfr[4];
        #pragma unroll
        for (int mi = 0; mi < 2; ++mi)
            #pragma unroll
            for (int ks = 0; ks < 4; ++ks) {
                const int row = mi * 32 + l5;
                af[mi][ks] = *reinterpret_cast<const bf16x8*>(
                    &As[cur][row][((ks * 2 + hi) ^ (row & 7)) * 8]);
            }
        #pragma unroll
        for (int ks = 0; ks < 4; ++ks) {
            const int row = wave * 32 + l5;
            bfr[ks] = *reinterpret_cast<const bf16x8*>(
                &Bs[cur][row][((ks * 2 + hi) ^ (row & 7)) * 8]);
        }
        __builtin_amdgcn_s_setprio(1);
        #pragma unroll
        for (int mi = 0; mi < 2; ++mi)
            #pragma unroll
            for (int ks = 0; ks < 4; ++ks)
                acc[mi] = __builtin_amdgcn_mfma_f32_32x32x16_bf16(
                    af[mi][ks], bfr[ks], acc[mi], 0, 0, 0);
        __builtin_amdgcn_s_setprio(0);
        __syncthreads();
    }

    #pragma unroll
    for (int mi = 0; mi < 2; ++mi)
        #pragma unroll
        for (int q = 0; q < 16; ++q) {
            const int m = m0 + mi * 32 + (q & 3) + 8 * (q >> 2) + 4 * hi;
            const int n = n0 + wave * 32 + l5;
            Out[(size_t)m * D_ + n] = acc[mi][q] + bo[n];
        }
}

// ======= flash attention: QBLK=64, 4 waves, 512 paired blocks (2/CU), XCD-grouped =======
// Block handles q-blocks pr and 31-pr sequentially (34 staged tiles, uniform).
// Softmax in log2 domain (Q pre-scaled by 0.125*log2e); p = v_exp_f32(s - m).
__global__ __launch_bounds__(256) void attn_kernel(
    const bf16* __restrict__ Q, const bf16* __restrict__ K,
    const bf16* __restrict__ Vt, bf16* __restrict__ Out)
{
    const int bid = blockIdx.x;
    const int xcd = bid & 7, j = bid >> 3;       // j 0..63
    const int bh  = xcd * 4 + (j >> 4);          // 4 bh per XCD
    const int pr  = j & 15;                      // pair index 0..15

    const int tid = threadIdx.x, wave = tid >> 6, lane = tid & 63;  // 4 waves
    const int lr = lane & 15, lg = lane >> 4;
    const size_t kbase = (size_t)bh * T_ * HD_;   // Q,K
    const size_t vbase = (size_t)bh * HD_ * T_;   // Vt

    __shared__ bf16 Ks[2][64][64];   // 16 KB
    __shared__ bf16 Vs[2][64][64];   // 16 KB  (Vs[buf][d][key])
    __shared__ bf16 Ps[4][16][72];   // 9 KB   per-wave P[q][key], padded

    auto stage = [&](int sb, int kt) {
        const int kv0 = kt * 64;
        const int rseg = lane >> 3;
        const int srcw = (lane & 7) ^ rseg;      // XOR source-chunk swizzle (involution)
        #pragma unroll
        for (int cc = 0; cc < 2; ++cc) {
            const int seg = wave * 2 + cc;       // 0..7
            const int row = seg * 8 + rseg;      // 0..63
            GLOAD_LDS(K  + kbase + (size_t)(kv0 + row) * HD_ + srcw * 8, &Ks[sb][seg * 8][0]);
            GLOAD_LDS(Vt + vbase + (size_t)row * T_ + kv0 + srcw * 8,    &Vs[sb][seg * 8][0]);
        }
    };
    auto kfrag = [&](int sb, int row, int chunk) {
        return *reinterpret_cast<const bf16x8*>(&Ks[sb][row][(chunk ^ (row & 7)) * 8]);
    };
    auto vfrag = [&](int sb, int row, int chunk) {
        return *reinterpret_cast<const bf16x8*>(&Vs[sb][row][(chunk ^ (row & 7)) * 8]);
    };

    #pragma unroll 1
    for (int half = 0; half < 2; ++half) {
        const int qb = half == 0 ? pr : (NQB - 1 - pr);
        const int q0 = qb * 64;
        const int nt = qb + 1;                   // tiles 0..qb (all active)
        const int qw = wave * 16;

        // Q fragments for this wave's 16 rows (B-operand: col=lane&15 -> q=lr)
        bf16x8 qf[2];
        {
            const bf16* qrow = Q + kbase + (size_t)(q0 + qw + lr) * HD_;
            qf[0] = *reinterpret_cast<const bf16x8*>(qrow + lg * 8);
            qf[1] = *reinterpret_cast<const bf16x8*>(qrow + 32 + lg * 8);
        }

        float m_s = -1e30f, l_s = 0.f;           // log2-domain state for q = q0+qw+lr
        f32x4 o_acc[4] = {};                     // O[q=qw+lg*4+r][d=nd*16+lr]

        stage(0, 0);
        __syncthreads();

        #pragma unroll 1
        for (int t = 0; t < nt; ++t) {
            const int cur = t & 1;
            if (t + 1 < nt) stage(cur ^ 1, t + 1);   // prefetch next tile

            const int kv0 = t * 64;
            // S'[key][q]: key = kv0 + n16*16 + lg*4 + r, q = q0 + qw + lr
            f32x4 s[4] = {};
            __builtin_amdgcn_s_setprio(1);
            #pragma unroll
            for (int n16 = 0; n16 < 4; ++n16)
                #pragma unroll
                for (int kk = 0; kk < 2; ++kk)
                    s[n16] = __builtin_amdgcn_mfma_f32_16x16x32_bf16(
                        kfrag(cur, n16 * 16 + lr, kk * 4 + lg), qf[kk], s[n16], 0, 0, 0);
            __builtin_amdgcn_s_setprio(0);
            if (t == qb) {                       // causal mask on diagonal tile
                #pragma unroll
                for (int n16 = 0; n16 < 4; ++n16)
                    #pragma unroll
                    for (int r = 0; r < 4; ++r)
                        if (kv0 + n16 * 16 + lg * 4 + r > q0 + qw + lr)
                            s[n16][r] = -1e30f;
            }
            // online softmax, log2 domain, defer-max (8 nats = 11.54 bits)
            float mx = s[0][0];
            #pragma unroll
            for (int n16 = 0; n16 < 4; ++n16)
                #pragma unroll
                for (int r = 0; r < 4; ++r)
                    mx = fmaxf(mx, s[n16][r]);
            mx = fmaxf(mx, __shfl_xor(mx, 16));
            mx = fmaxf(mx, __shfl_xor(mx, 32));
            if (__any(mx > m_s + 11.5416f)) {
                const float mnew  = fmaxf(m_s, mx);
                const float alpha = exp2_fast(m_s - mnew);
                #pragma unroll
                for (int r = 0; r < 4; ++r) {
                    const float a = __shfl(alpha, lg * 4 + r);
                    #pragma unroll
                    for (int nd = 0; nd < 4; ++nd) o_acc[nd][r] *= a;
                }
                l_s *= alpha;
                m_s = mnew;
            }
            float rs = 0.f;
            #pragma unroll
            for (int n16 = 0; n16 < 4; ++n16) {
                bf16x4 pw;
                #pragma unroll
                for (int r = 0; r < 4; ++r) {
                    const float p = exp2_fast(s[n16][r] - m_s);   // bounded by 2^11.54
                    rs += p;
                    pw[r] = (bf16)p;
                }
                *reinterpret_cast<bf16x4*>(&Ps[wave][lr][n16 * 16 + lg * 4]) = pw;
            }
            rs += __shfl_xor(rs, 16);
            rs += __shfl_xor(rs, 32);
            l_s += rs;
            // O += P @ V
            __builtin_amdgcn_s_setprio(1);
            #pragma unroll
            for (int ks = 0; ks < 2; ++ks) {
                const bf16x8 pa = *reinterpret_cast<const bf16x8*>(&Ps[wave][lr][ks * 32 + lg * 8]);
                #pragma unroll
                for (int nd = 0; nd < 4; ++nd)
                    o_acc[nd] = __builtin_amdgcn_mfma_f32_16x16x32_bf16(
                        pa, vfrag(cur, nd * 16 + lr, ks * 4 + lg), o_acc[nd], 0, 0, 0);
            }
            __builtin_amdgcn_s_setprio(0);
            __syncthreads();   // all reads of cur done; next tile fully staged
        }

        // normalize + store to [b*T+t][h*64+d]
        const int b = bh >> 4, h = bh & 15;
        const float linv = 1.0f / l_s;
        #pragma unroll
        for (int r = 0; r < 4; ++r) {
            const float li = __shfl(linv, lg * 4 + r);
            const int q = q0 + qw + lg * 4 + r;
            #pragma unroll
            for (int nd = 0; nd < 4; ++nd) {
                const int d = nd * 16 + lr;
                Out[((size_t)(b * T_ + q)) * D_ + h * HD_ + d] = (bf16)(o_acc[nd][r] * li);
            }
        }
    }
}

// ---------------- launch ----------------
extern "C" void kernel_launch(void* const* d_in, const int* in_sizes, int n_in,
                              void* d_out, int out_size, void* d_ws, size_t ws_size,
                              hipStream_t stream) {
    const float* x  = (const float*)d_in[0];
    const float* Wq = (const float*)d_in[1];
    const float* bq = (const float*)d_in[2];
    const float* Wk = (const float*)d_in[3];
    const float* bk = (const float*)d_in[4];
    const float* Wv = (const float*)d_in[5];
    const float* bv = (const float*)d_in[6];
    const float* Wo = (const float*)d_in[7];
    const float* bo = (const float*)d_in[8];
    float* out = (float*)d_out;

    char* ws = (char*)d_ws;
    bf16* xb   = (bf16*)(ws);                         // 8 MB  [4096][1024]
    bf16* WqT  = (bf16*)(ws + ( 8u << 20));           // 2 MB  [1024][1024]
    bf16* WkT  = (bf16*)(ws + (10u << 20));
    bf16* WvT  = (bf16*)(ws + (12u << 20));
    bf16* WoT  = (bf16*)(ws + (14u << 20));
    bf16* Qb   = (bf16*)(ws + (16u << 20));           // 8 MB  [32][2048][64]
    bf16* Kb   = (bf16*)(ws + (24u << 20));
    bf16* Vtb  = (bf16*)(ws + (32u << 20));           // 8 MB  [32][64][2048]
    bf16* attn = (bf16*)(ws + (40u << 20));           // 8 MB  [4096][1024]

    prep_kernel<<<dim3(32, 32, 5), 256, 0, stream>>>(
        x, xb, Wq, WqT, Wk, WkT, Wv, WvT, Wo, WoT);

    qkv128_kernel<<<768, 256, 0, stream>>>(xb, WqT, bq, Qb, WkT, bk, Kb, WvT, bv, Vtb);

    attn_kernel<<<512, 256, 0, stream>>>(Qb, Kb, Vtb, attn);

    gemm_out_kernel<<<512, 256, 0, stream>>>(attn, WoT, bo, out);
}

// Round 19
// 122.653 us; speedup vs baseline: 1.2200x; 1.0085x over previous
//
#include <hip/hip_runtime.h>
#include <cstdint>
#include <cstddef>

typedef __bf16 bf16;
typedef __bf16 bf16x4 __attribute__((ext_vector_type(4)));
typedef __bf16 bf16x8 __attribute__((ext_vector_type(8)));
typedef float  f32x4  __attribute__((ext_vector_type(4)));
typedef float  f32x16 __attribute__((ext_vector_type(16)));

#define B_  2
#define T_  2048
#define D_  1024
#define H_  16
#define HD_ 64
#define M_  (B_ * T_)   // 4096 rows
#define NQB 32          // T_/64 q-blocks

#define GLOAD_LDS(gsrc, ldst) \
    __builtin_amdgcn_global_load_lds( \
        (const __attribute__((address_space(1))) void*)(gsrc), \
        (__attribute__((address_space(3))) void*)(ldst), 16, 0, 0)

// fast 2^x: single v_exp_f32 (ISA: D = 2^S0), no libm range handling
__device__ __forceinline__ float exp2_fast(float x) {
    float r;
    asm("v_exp_f32 %0, %1" : "=v"(r) : "v"(x));
    return r;
}

// ------- merged prologue: z<4 -> transpose+cast W_z; z==4 -> cast x -------
__global__ void prep_kernel(
    const float* __restrict__ x,  bf16* __restrict__ xb,
    const float* __restrict__ W0, bf16* __restrict__ T0,
    const float* __restrict__ W1, bf16* __restrict__ T1,
    const float* __restrict__ W2, bf16* __restrict__ T2,
    const float* __restrict__ W3, bf16* __restrict__ T3)
{
    if (blockIdx.z == 4) {
        const int linear = blockIdx.y * 32 + blockIdx.x;
        const int base = linear * 4096 + threadIdx.x * 4;
        #pragma unroll
        for (int u = 0; u < 4; ++u) {
            const int i = base + u * 1024;
            const float4 v = *reinterpret_cast<const float4*>(x + i);
            bf16x4 o = { (bf16)v.x, (bf16)v.y, (bf16)v.z, (bf16)v.w };
            *reinterpret_cast<bf16x4*>(xb + i) = o;
        }
        return;
    }
    __shared__ float tile[32][33];
    const float* W = blockIdx.z == 0 ? W0 : blockIdx.z == 1 ? W1 : blockIdx.z == 2 ? W2 : W3;
    bf16*       Wt = blockIdx.z == 0 ? T0 : blockIdx.z == 1 ? T1 : blockIdx.z == 2 ? T2 : T3;
    const int tx = threadIdx.x & 31, ty = threadIdx.x >> 5;  // 32 x 8
    const int bx = blockIdx.x * 32, by = blockIdx.y * 32;
    #pragma unroll
    for (int r = 0; r < 32; r += 8)
        tile[ty + r][tx] = W[(size_t)(by + ty + r) * D_ + bx + tx];
    __syncthreads();
    #pragma unroll
    for (int r = 0; r < 32; r += 8)
        Wt[(size_t)(bx + ty + r) * D_ + by + tx] = (bf16)tile[tx][ty + r];
}

// ======== 128x128 bf16 GEMM core, 8 waves (64x32/wave), 2-phase dbuf, T2 swizzle ========
// acc[mi] covers rows wr*64+mi*32, cols wc*32 (wr=wave>>2, wc=wave&3).
__device__ __forceinline__ void gemm_128_8w(
    const bf16* __restrict__ A, const bf16* __restrict__ Bt,
    int m0, int n0, bf16 (*As)[128][64], bf16 (*Bs)[128][64], f32x16 acc[2])
{
    constexpr int K = D_;
    constexpr int NK = K / 64;
    const int tid  = threadIdx.x;
    const int wave = tid >> 6, lane = tid & 63;
    const int l5 = lane & 31, hi = lane >> 5;
    const int wr = wave >> 2, wc = wave & 3;

    const int rseg = lane >> 3;              // 0..7
    const int srcc = (lane & 7) ^ rseg;      // pre-swizzled source chunk

    auto stage = [&](int b, int k0) {
        #pragma unroll
        for (int cc = 0; cc < 2; ++cc) {     // 16 segs per matrix, 2 per wave
            const int c   = wave * 2 + cc;
            const int row = c * 8 + rseg;
            GLOAD_LDS(A  + (size_t)(m0 + row) * K + k0 + srcc * 8, &As[b][c * 8][0]);
            GLOAD_LDS(Bt + (size_t)(n0 + row) * K + k0 + srcc * 8, &Bs[b][c * 8][0]);
        }
    };

    stage(0, 0);
    __syncthreads();

    #pragma unroll 1
    for (int t = 0; t < NK; ++t) {
        const int cur = t & 1;
        if (t + 1 < NK) stage(cur ^ 1, (t + 1) * 64);   // prefetch next tile first

        bf16x8 af[2][4], bfr[4];
        #pragma unroll
        for (int mi = 0; mi < 2; ++mi)
            #pragma unroll
            for (int ks = 0; ks < 4; ++ks) {
                const int row = wr * 64 + mi * 32 + l5;
                af[mi][ks] = *reinterpret_cast<const bf16x8*>(
                    &As[cur][row][((ks * 2 + hi) ^ (row & 7)) * 8]);
            }
        #pragma unroll
        for (int ks = 0; ks < 4; ++ks) {
            const int row = wc * 32 + l5;
            bfr[ks] = *reinterpret_cast<const bf16x8*>(
                &Bs[cur][row][((ks * 2 + hi) ^ (row & 7)) * 8]);
        }
        __builtin_amdgcn_s_setprio(1);
        #pragma unroll
        for (int mi = 0; mi < 2; ++mi)
            #pragma unroll
            for (int ks = 0; ks < 4; ++ks)
                acc[mi] = __builtin_amdgcn_mfma_f32_32x32x16_bf16(
                    af[mi][ks], bfr[ks], acc[mi], 0, 0, 0);
        __builtin_amdgcn_s_setprio(0);
        __syncthreads();
    }
}

// ================= fused QKV projection, 128^2 tiles, 768 x 512-thread blocks =================
__global__ __launch_bounds__(512, 2) void qkv128_kernel(
    const bf16* __restrict__ xb,
    const bf16* __restrict__ WqT, const float* __restrict__ bq, bf16* __restrict__ Qo,
    const bf16* __restrict__ WkT, const float* __restrict__ bk, bf16* __restrict__ Ko,
    const bf16* __restrict__ WvT, const float* __restrict__ bv, bf16* __restrict__ Vt)
{
    __shared__ bf16 As[2][128][64];   // 32 KB
    __shared__ bf16 Bs[2][128][64];   // 32 KB

    const int bid = blockIdx.x;
    const int swz = (bid & 7) * 96 + (bid >> 3);   // XCD-bijective (768 % 8 == 0)

    const bf16 *Aop, *Bop;
    const float *bias;
    bf16 *outp;
    float scale = 1.0f;
    int m0, n0, mode;
    if (swz < 512) {
        const int bm = swz & 31, bn = swz >> 5;    // bm 0..31 (tokens), bn 0..15 (Q|K)
        m0 = bm * 128;
        Aop = xb;
        if (bn < 8) { Bop = WqT; n0 = bn * 128;       bias = bq; outp = Qo;
                      scale = 0.125f * 1.44269504f; }   // fold log2e for exp2 softmax
        else        { Bop = WkT; n0 = (bn - 8) * 128; bias = bk; outp = Ko; }
        mode = 0;
    } else {
        const int v = swz - 512, bm = v & 7, bn = v >> 3;  // bm 0..7 (d), bn 0..31 (tokens)
        m0 = bm * 128; n0 = bn * 128;
        Aop = WvT; Bop = xb; bias = bv; outp = Vt; mode = 1;
    }

    f32x16 acc[2] = {};
    gemm_128_8w(Aop, Bop, m0, n0, As, Bs, acc);

    const int lane = threadIdx.x & 63, wave = threadIdx.x >> 6;
    const int l5 = lane & 31, hi = lane >> 5;
    const int wr = wave >> 2, wc = wave & 3;
    if (mode == 0) {
        #pragma unroll
        for (int mi = 0; mi < 2; ++mi)
            #pragma unroll
            for (int q = 0; q < 16; ++q) {
                const int m = m0 + wr * 64 + mi * 32 + (q & 3) + 8 * (q >> 2) + 4 * hi;
                const int n = n0 + wc * 32 + l5;
                const float val = (acc[mi][q] + bias[n]) * scale;
                const int b = m >> 11, t = m & (T_ - 1);
                const int h = n >> 6, hd = n & 63;
                outp[((size_t)((b * H_ + h) * T_ + t)) * HD_ + hd] = (bf16)val;
            }
    } else {
        #pragma unroll
        for (int mi = 0; mi < 2; ++mi)
            #pragma unroll
            for (int q = 0; q < 16; ++q) {
                const int d = m0 + wr * 64 + mi * 32 + (q & 3) + 8 * (q >> 2) + 4 * hi;
                const int n = n0 + wc * 32 + l5;
                const float val = acc[mi][q] + bias[d];
                const int b = n >> 11, t = n & (T_ - 1);
                outp[((size_t)(b * D_ + d)) * T_ + t] = (bf16)val;
            }
    }
}

// ========= out projection: BM=64 x BN=128 tiles, 512 blocks (2/CU), fp32 out =========
__global__ __launch_bounds__(256, 2) void gemm_out_kernel(
    const bf16* __restrict__ A, const bf16* __restrict__ WoT,
    const float* __restrict__ bo, float* __restrict__ Out)
{
    constexpr int K = D_;
    constexpr int NK = K / 64;
    __shared__ bf16 As[2][64][64];    // 16 KB
    __shared__ bf16 Bs[2][128][64];   // 32 KB

    const int bid = blockIdx.x;
    const int swz = (bid & 7) * 64 + (bid >> 3);   // XCD-bijective (512 % 8 == 0)
    const int m0 = (swz & 63) * 64, n0 = (swz >> 6) * 128;

    const int tid = threadIdx.x, wave = tid >> 6, lane = tid & 63;
    const int l5 = lane & 31, hi = lane >> 5;
    const int rseg = lane >> 3;
    const int srcc = (lane & 7) ^ rseg;

    auto stage = [&](int b, int k0) {
        #pragma unroll
        for (int cc = 0; cc < 2; ++cc) {       // A: 8 segs, 2/wave
            const int seg = wave * 2 + cc;
            const int row = seg * 8 + rseg;
            GLOAD_LDS(A + (size_t)(m0 + row) * K + k0 + srcc * 8, &As[b][seg * 8][0]);
        }
        #pragma unroll
        for (int cc = 0; cc < 4; ++cc) {       // B: 16 segs, 4/wave
            const int seg = wave * 4 + cc;
            const int row = seg * 8 + rseg;
            GLOAD_LDS(WoT + (size_t)(n0 + row) * K + k0 + srcc * 8, &Bs[b][seg * 8][0]);
        }
    };

    f32x16 acc[2] = {};
    stage(0, 0);
    __syncthreads();

    #pragma unroll 1
    for (int t = 0; t < NK; ++t) {
        const int cur = t & 1;
        if (t + 1 < NK) stage(cur ^ 1, (t + 1) * 64);

        bf16x8 af[2][4], bfr[4];
        #pragma unroll
        for (int mi = 0; mi < 2; ++mi)
            #pragma unroll
            for (int ks = 0; ks < 4; ++ks) {
                const int row = mi * 32 + l5;
                af[mi][ks] = *reinterpret_cast<const bf16x8*>(
                    &As[cur][row][((ks * 2 + hi) ^ (row & 7)) * 8]);
            }
        #pragma unroll
        for (int ks = 0; ks < 4; ++ks) {
            const int row = wave * 32 + l5;
            bfr[ks] = *reinterpret_cast<const bf16x8*>(
                &Bs[cur][row][((ks * 2 + hi) ^ (row & 7)) * 8]);
        }
        __builtin_amdgcn_s_setprio(1);
        #pragma unroll
        for (int mi = 0; mi < 2; ++mi)
            #pragma unroll
            for (int ks = 0; ks < 4; ++ks)
                acc[mi] = __builtin_amdgcn_mfma_f32_32x32x16_bf16(
                    af[mi][ks], bfr[ks], acc[mi], 0, 0, 0);
        __builtin_amdgcn_s_setprio(0);
        __syncthreads();
    }

    #pragma unroll
    for (int mi = 0; mi < 2; ++mi)
        #pragma unroll
        for (int q = 0; q < 16; ++q) {
            const int m = m0 + mi * 32 + (q & 3) + 8 * (q >> 2) + 4 * hi;
            const int n = n0 + wave * 32 + l5;
            Out[(size_t)m * D_ + n] = acc[mi][q] + bo[n];
        }
}

// ======= flash attention: QBLK=64, 4 waves, 512 paired blocks (2/CU), XCD-grouped =======
// Block handles q-blocks pr and 31-pr sequentially (34 staged tiles, uniform).
// Softmax in log2 domain (Q pre-scaled by 0.125*log2e); p = v_exp_f32(s - m).
__global__ __launch_bounds__(256) void attn_kernel(
    const bf16* __restrict__ Q, const bf16* __restrict__ K,
    const bf16* __restrict__ Vt, bf16* __restrict__ Out)
{
    const int bid = blockIdx.x;
    const int xcd = bid & 7, j = bid >> 3;       // j 0..63
    const int bh  = xcd * 4 + (j >> 4);          // 4 bh per XCD
    const int pr  = j & 15;                      // pair index 0..15

    const int tid = threadIdx.x, wave = tid >> 6, lane = tid & 63;  // 4 waves
    const int lr = lane & 15, lg = lane >> 4;
    const size_t kbase = (size_t)bh * T_ * HD_;   // Q,K
    const size_t vbase = (size_t)bh * HD_ * T_;   // Vt

    __shared__ bf16 Ks[2][64][64];   // 16 KB
    __shared__ bf16 Vs[2][64][64];   // 16 KB  (Vs[buf][d][key])
    __shared__ bf16 Ps[4][16][72];   // 9 KB   per-wave P[q][key], padded

    auto stage = [&](int sb, int kt) {
        const int kv0 = kt * 64;
        const int rseg = lane >> 3;
        const int srcw = (lane & 7) ^ rseg;      // XOR source-chunk swizzle (involution)
        #pragma unroll
        for (int cc = 0; cc < 2; ++cc) {
            const int seg = wave * 2 + cc;       // 0..7
            const int row = seg * 8 + rseg;      // 0..63
            GLOAD_LDS(K  + kbase + (size_t)(kv0 + row) * HD_ + srcw * 8, &Ks[sb][seg * 8][0]);
            GLOAD_LDS(Vt + vbase + (size_t)row * T_ + kv0 + srcw * 8,    &Vs[sb][seg * 8][0]);
        }
    };
    auto kfrag = [&](int sb, int row, int chunk) {
        return *reinterpret_cast<const bf16x8*>(&Ks[sb][row][(chunk ^ (row & 7)) * 8]);
    };
    auto vfrag = [&](int sb, int row, int chunk) {
        return *reinterpret_cast<const bf16x8*>(&Vs[sb][row][(chunk ^ (row & 7)) * 8]);
    };

    #pragma unroll 1
    for (int half = 0; half < 2; ++half) {
        const int qb = half == 0 ? pr : (NQB - 1 - pr);
        const int q0 = qb * 64;
        const int nt = qb + 1;                   // tiles 0..qb (all active)
        const int qw = wave * 16;

        // Q fragments for this wave's 16 rows (B-operand: col=lane&15 -> q=lr)
        bf16x8 qf[2];
        {
            const bf16* qrow = Q + kbase + (size_t)(q0 + qw + lr) * HD_;
            qf[0] = *reinterpret_cast<const bf16x8*>(qrow + lg * 8);
            qf[1] = *reinterpret_cast<const bf16x8*>(qrow + 32 + lg * 8);
        }

        float m_s = -1e30f, l_s = 0.f;           // log2-domain state for q = q0+qw+lr
        f32x4 o_acc[4] = {};                     // O[q=qw+lg*4+r][d=nd*16+lr]

        stage(0, 0);
        __syncthreads();

        #pragma unroll 1
        for (int t = 0; t < nt; ++t) {
            const int cur = t & 1;
            if (t + 1 < nt) stage(cur ^ 1, t + 1);   // prefetch next tile

            const int kv0 = t * 64;
            // S'[key][q]: key = kv0 + n16*16 + lg*4 + r, q = q0 + qw + lr
            f32x4 s[4] = {};
            __builtin_amdgcn_s_setprio(1);
            #pragma unroll
            for (int n16 = 0; n16 < 4; ++n16)
                #pragma unroll
                for (int kk = 0; kk < 2; ++kk)
                    s[n16] = __builtin_amdgcn_mfma_f32_16x16x32_bf16(
                        kfrag(cur, n16 * 16 + lr, kk * 4 + lg), qf[kk], s[n16], 0, 0, 0);
            __builtin_amdgcn_s_setprio(0);
            if (t == qb) {                       // causal mask on diagonal tile
                #pragma unroll
                for (int n16 = 0; n16 < 4; ++n16)
                    #pragma unroll
                    for (int r = 0; r < 4; ++r)
                        if (kv0 + n16 * 16 + lg * 4 + r > q0 + qw + lr)
                            s[n16][r] = -1e30f;
            }
            // online softmax, log2 domain, defer-max (8 nats = 11.54 bits)
            float mx = s[0][0];
            #pragma unroll
            for (int n16 = 0; n16 < 4; ++n16)
                #pragma unroll
                for (int r = 0; r < 4; ++r)
                    mx = fmaxf(mx, s[n16][r]);
            mx = fmaxf(mx, __shfl_xor(mx, 16));
            mx = fmaxf(mx, __shfl_xor(mx, 32));
            if (__any(mx > m_s + 11.5416f)) {
                const float mnew  = fmaxf(m_s, mx);
                const float alpha = exp2_fast(m_s - mnew);
                #pragma unroll
                for (int r = 0; r < 4; ++r) {
                    const float a = __shfl(alpha, lg * 4 + r);
                    #pragma unroll
                    for (int nd = 0; nd < 4; ++nd) o_acc[nd][r] *= a;
                }
                l_s *= alpha;
                m_s = mnew;
            }
            float rs = 0.f;
            #pragma unroll
            for (int n16 = 0; n16 < 4; ++n16) {
                bf16x4 pw;
                #pragma unroll
                for (int r = 0; r < 4; ++r) {
                    const float p = exp2_fast(s[n16][r] - m_s);   // bounded by 2^11.54
                    rs += p;
                    pw[r] = (bf16)p;
                }
                *reinterpret_cast<bf16x4*>(&Ps[wave][lr][n16 * 16 + lg * 4]) = pw;
            }
            rs += __shfl_xor(rs, 16);
            rs += __shfl_xor(rs, 32);
            l_s += rs;
            // O += P @ V
            __builtin_amdgcn_s_setprio(1);
            #pragma unroll
            for (int ks = 0; ks < 2; ++ks) {
                const bf16x8 pa = *reinterpret_cast<const bf16x8*>(&Ps[wave][lr][ks * 32 + lg * 8]);
                #pragma unroll
                for (int nd = 0; nd < 4; ++nd)
                    o_acc[nd] = __builtin_amdgcn_mfma_f32_16x16x32_bf16(
                        pa, vfrag(cur, nd * 16 + lr, ks * 4 + lg), o_acc[nd], 0, 0, 0);
            }
            __builtin_amdgcn_s_setprio(0);
            __syncthreads();   // all reads of cur done; next tile fully staged
        }

        // normalize + store to [b*T+t][h*64+d]
        const int b = bh >> 4, h = bh & 15;
        const float linv = 1.0f / l_s;
        #pragma unroll
        for (int r = 0; r < 4; ++r) {
            const float li = __shfl(linv, lg * 4 + r);
            const int q = q0 + qw + lg * 4 + r;
            #pragma unroll
            for (int nd = 0; nd < 4; ++nd) {
                const int d = nd * 16 + lr;
                Out[((size_t)(b * T_ + q)) * D_ + h * HD_ + d] = (bf16)(o_acc[nd][r] * li);
            }
        }
    }
}

// ---------------- launch ----------------
extern "C" void kernel_launch(void* const* d_in, const int* in_sizes, int n_in,
                              void* d_out, int out_size, void* d_ws, size_t ws_size,
                              hipStream_t stream) {
    const float* x  = (const float*)d_in[0];
    const float* Wq = (const float*)d_in[1];
    const float* bq = (const float*)d_in[2];
    const float* Wk = (const float*)d_in[3];
    const float* bk = (const float*)d_in[4];
    const float* Wv = (const float*)d_in[5];
    const float* bv = (const float*)d_in[6];
    const float* Wo = (const float*)d_in[7];
    const float* bo = (const float*)d_in[8];
    float* out = (float*)d_out;

    char* ws = (char*)d_ws;
    bf16* xb   = (bf16*)(ws);                         // 8 MB  [4096][1024]
    bf16* WqT  = (bf16*)(ws + ( 8u << 20));           // 2 MB  [1024][1024]
    bf16* WkT  = (bf16*)(ws + (10u << 20));
    bf16* WvT  = (bf16*)(ws + (12u << 20));
    bf16* WoT  = (bf16*)(ws + (14u << 20));
    bf16* Qb   = (bf16*)(ws + (16u << 20));           // 8 MB  [32][2048][64]
    bf16* Kb   = (bf16*)(ws + (24u << 20));
    bf16* Vtb  = (bf16*)(ws + (32u << 20));           // 8 MB  [32][64][2048]
    bf16* attn = (bf16*)(ws + (40u << 20));           // 8 MB  [4096][1024]

    prep_kernel<<<dim3(32, 32, 5), 256, 0, stream>>>(
        x, xb, Wq, WqT, Wk, WkT, Wv, WvT, Wo, WoT);

    qkv128_kernel<<<768, 512, 0, stream>>>(xb, WqT, bq, Qb, WkT, bk, Kb, WvT, bv, Vtb);

    attn_kernel<<<512, 256, 0, stream>>>(Qb, Kb, Vtb, attn);

    gemm_out_kernel<<<512, 256, 0, stream>>>(attn, WoT, bo, out);
}

// Round 20
// 111.289 us; speedup vs baseline: 1.3445x; 1.1021x over previous
//
#include <hip/hip_runtime.h>
#include <cstdint>
#include <cstddef>

typedef __bf16 bf16;
typedef __bf16 bf16x4 __attribute__((ext_vector_type(4)));
typedef __bf16 bf16x8 __attribute__((ext_vector_type(8)));
typedef float  f32x4  __attribute__((ext_vector_type(4)));
typedef float  f32x16 __attribute__((ext_vector_type(16)));

#define B_  2
#define T_  2048
#define D_  1024
#define H_  16
#define HD_ 64
#define M_  (B_ * T_)   // 4096 rows
#define NQB 32          // T_/64 q-blocks

#define GLOAD_LDS(gsrc, ldst) \
    __builtin_amdgcn_global_load_lds( \
        (const __attribute__((address_space(1))) void*)(gsrc), \
        (__attribute__((address_space(3))) void*)(ldst), 16, 0, 0)

// fast 2^x: single v_exp_f32 (ISA: D = 2^S0), no libm range handling
__device__ __forceinline__ float exp2_fast(float x) {
    float r;
    asm("v_exp_f32 %0, %1" : "=v"(r) : "v"(x));
    return r;
}

__device__ __forceinline__ void barrier_pin() {
    asm volatile("" ::: "memory");
    __builtin_amdgcn_s_barrier();
    asm volatile("" ::: "memory");
}

// ------- merged prologue: z<4 -> transpose+cast W_z; z==4 -> cast x -------
__global__ void prep_kernel(
    const float* __restrict__ x,  bf16* __restrict__ xb,
    const float* __restrict__ W0, bf16* __restrict__ T0,
    const float* __restrict__ W1, bf16* __restrict__ T1,
    const float* __restrict__ W2, bf16* __restrict__ T2,
    const float* __restrict__ W3, bf16* __restrict__ T3)
{
    if (blockIdx.z == 4) {
        const int linear = blockIdx.y * 32 + blockIdx.x;
        const int base = linear * 4096 + threadIdx.x * 4;
        #pragma unroll
        for (int u = 0; u < 4; ++u) {
            const int i = base + u * 1024;
            const float4 v = *reinterpret_cast<const float4*>(x + i);
            bf16x4 o = { (bf16)v.x, (bf16)v.y, (bf16)v.z, (bf16)v.w };
            *reinterpret_cast<bf16x4*>(xb + i) = o;
        }
        return;
    }
    __shared__ float tile[32][33];
    const float* W = blockIdx.z == 0 ? W0 : blockIdx.z == 1 ? W1 : blockIdx.z == 2 ? W2 : W3;
    bf16*       Wt = blockIdx.z == 0 ? T0 : blockIdx.z == 1 ? T1 : blockIdx.z == 2 ? T2 : T3;
    const int tx = threadIdx.x & 31, ty = threadIdx.x >> 5;  // 32 x 8
    const int bx = blockIdx.x * 32, by = blockIdx.y * 32;
    #pragma unroll
    for (int r = 0; r < 32; r += 8)
        tile[ty + r][tx] = W[(size_t)(by + ty + r) * D_ + bx + tx];
    __syncthreads();
    #pragma unroll
    for (int r = 0; r < 32; r += 8)
        Wt[(size_t)(bx + ty + r) * D_ + by + tx] = (bf16)tile[tx][ty + r];
}

// ================= 256x256 8-phase QKV kernel (T2+T3+T4+T5, m201-faithful) =================
// swz < 128: QK (A = xb tokens, Bt = WqT/WkT); swz >= 128: V^T (A = WvT, Bt = xb).
// BM=BN=256, BK=64, 8 waves (2Mx4N), LDS = 2dbuf x 2half x 128x64 x {A,B} = 128 KiB.
// A-halves = 64-row stripes {h*64, 128+h*64}; B-halves = 32-row stripes (4x).
// Per tile t (buffer c): p0 {LDA0,LDB0 | stage A[cn][1](t+1)} -> quad(A0,B0)
//                        p1 {LDB1      | stage B[cn][0](t+1)} -> quad(A0,B1)
//                        p2 {LDA1      | stage A[c ][0](t+2)} -> quad(A1,B1)
//                        p3 {          | stage B[c ][1](t+2); vmcnt(4)} -> quad(A1,B0)
// ds_reads issued BEFORE the barrier (latency hides under barrier wait);
// vmcnt(4) at p3 = wait tile t+1's 4 half-tiles, leave t+2's 2 stages in flight.
__global__ __launch_bounds__(512, 2) void qkv256_kernel(
    const bf16* __restrict__ xb,
    const bf16* __restrict__ WqT, const float* __restrict__ bq, bf16* __restrict__ Qo,
    const bf16* __restrict__ WkT, const float* __restrict__ bk, bf16* __restrict__ Ko,
    const bf16* __restrict__ WvT, const float* __restrict__ bv, bf16* __restrict__ Vt)
{
    __shared__ bf16 As[2][2][128][64];   // 64 KiB
    __shared__ bf16 Bs[2][2][128][64];   // 64 KiB

    const int bid = blockIdx.x;
    const int swz = (bid & 7) * 24 + (bid >> 3);       // XCD-bijective (192 % 8 == 0)
    const int tid = threadIdx.x, wave = tid >> 6, lane = tid & 63;
    const int lr = lane & 15, lg = lane >> 4;
    const int wr = wave >> 2, wc = wave & 3;

    const bf16 *Aop, *Bop;
    const float *bias;
    bf16 *outp;
    float scale = 1.0f;
    int mbase, nbase, mode;
    if (swz < 128) {
        const int bm = swz >> 3, bn = swz & 7;
        mbase = bm * 256;                               // token rows
        nbase = (bn & 3) * 256;                         // col within Wq or Wk
        Aop = xb + (size_t)mbase * D_;
        if (bn < 4) { Bop = WqT + (size_t)nbase * D_; bias = bq; outp = Qo;
                      scale = 0.125f * 1.44269504f; }   // log2e folded for exp2 softmax
        else        { Bop = WkT + (size_t)nbase * D_; bias = bk; outp = Ko; }
        mode = 0;
    } else {
        const int v = swz - 128, bm = v >> 4, bn = v & 15;
        mbase = bm * 256;                               // d rows
        nbase = bn * 256;                               // token cols
        Aop = WvT + (size_t)mbase * D_;
        Bop = xb  + (size_t)nbase * D_;
        bias = bv; outp = Vt; mode = 1;
    }

    // ---- staging: one half-tile = 2 gload_lds per wave; XOR source-chunk swizzle ----
    const int r8   = lane >> 3;
    const int srcc = (lane & 7) ^ r8;
    auto stageA = [&](int c, int h, int kt) {
        #pragma unroll
        for (int l = 0; l < 2; ++l) {
            const int cr  = wave * 2 + l;
            const int loc = cr * 8 + r8;                            // 0..127
            const int rho = h * 64 + (loc & 63) + ((loc >> 6) << 7); // stripe map
            GLOAD_LDS(Aop + (size_t)rho * D_ + kt * 64 + srcc * 8, &As[c][h][cr * 8][0]);
        }
    };
    auto stageB = [&](int c, int h, int kt) {
        #pragma unroll
        for (int l = 0; l < 2; ++l) {
            const int cr  = wave * 2 + l;
            const int loc = cr * 8 + r8;
            const int rho = h * 32 + (loc & 31) + ((loc >> 5) << 6);
            GLOAD_LDS(Bop + (size_t)rho * D_ + kt * 64 + srcc * 8, &Bs[c][h][cr * 8][0]);
        }
    };

    f32x4 acc[8][4] = {};
    bf16x8 ar[4][2], b0r[2][2], b1r[2][2];

    auto LDA = [&](int c, int mh) {
        #pragma unroll
        for (int i = 0; i < 4; ++i)
            #pragma unroll
            for (int kk = 0; kk < 2; ++kk)
                ar[i][kk] = *reinterpret_cast<const bf16x8*>(
                    &As[c][mh][wr * 64 + i * 16 + lr][(((kk * 4 + lg)) ^ (lr & 7)) * 8]);
    };
    auto LDB = [&](int c, int nh, bf16x8 (&br)[2][2]) {
        #pragma unroll
        for (int j = 0; j < 2; ++j)
            #pragma unroll
            for (int kk = 0; kk < 2; ++kk)
                br[j][kk] = *reinterpret_cast<const bf16x8*>(
                    &Bs[c][nh][wc * 32 + j * 16 + lr][(((kk * 4 + lg)) ^ (lr & 7)) * 8]);
    };
    auto QUAD = [&](const bf16x8 (&br)[2][2], int mh, int nh) {
        __builtin_amdgcn_s_setprio(1);
        #pragma unroll
        for (int i = 0; i < 4; ++i)
            #pragma unroll
            for (int j = 0; j < 2; ++j)
                #pragma unroll
                for (int kk = 0; kk < 2; ++kk)
                    acc[mh * 4 + i][nh * 2 + j] = __builtin_amdgcn_mfma_f32_16x16x32_bf16(
                        ar[i][kk], br[j][kk], acc[mh * 4 + i][nh * 2 + j], 0, 0, 0);
        __builtin_amdgcn_s_setprio(0);
    };

    constexpr int NK = D_ / 64;   // 16 K-tiles
    // prologue: tile0 all 4 halves + tile1's {A0, B1} (the "t-1 p2/p3" stages)
    stageA(0, 0, 0); stageB(0, 0, 0); stageA(0, 1, 0); stageB(0, 1, 0);
    stageA(1, 0, 1); stageB(1, 1, 1);
    asm volatile("s_waitcnt vmcnt(4)" ::: "memory");   // tile0 resident; t1's 2 stages in flight
    barrier_pin();

    #pragma unroll 1
    for (int t = 0; t < NK; ++t) {
        const int c = t & 1, cn = c ^ 1;
        const int t1 = (t + 1 < NK) ? t + 1 : NK - 1;   // clamped stages overwrite dead halves only
        const int t2 = (t + 2 < NK) ? t + 2 : NK - 1;
        // ---- phase 0: quad (A0,B0); reads BEFORE barrier ----
        LDA(c, 0); LDB(c, 0, b0r);
        stageA(cn, 1, t1);
        barrier_pin();
        QUAD(b0r, 0, 0);
        barrier_pin();
        // ---- phase 1: quad (A0,B1) ----
        LDB(c, 1, b1r);
        stageB(cn, 0, t1);
        barrier_pin();
        QUAD(b1r, 0, 1);
        barrier_pin();
        // ---- phase 2: quad (A1,B1) ----
        LDA(c, 1);
        stageA(c, 0, t2);        // A[c][0] dead since p0 (in regs)
        barrier_pin();
        QUAD(b1r, 1, 1);
        barrier_pin();
        // ---- phase 3: quad (A1,B0); B0 still in regs from p0 ----
        stageB(c, 1, t2);        // B[c][1] dead since p1 (in regs)
        asm volatile("s_waitcnt vmcnt(4)" ::: "memory");   // tile t+1 fully resident
        barrier_pin();
        QUAD(b0r, 1, 0);
        barrier_pin();
    }

    // ---- epilogue (r4-verified mappings) ----
    if (mode == 0) {
        #pragma unroll
        for (int i = 0; i < 8; ++i)
            #pragma unroll
            for (int j = 0; j < 4; ++j)
                #pragma unroll
                for (int r = 0; r < 4; ++r) {
                    const int m  = mbase + wr * 128 + i * 16 + lg * 4 + r;   // token
                    const int nw = nbase + wc * 64 + j * 16 + lr;            // 0..1023
                    const float val = (acc[i][j][r] + bias[nw]) * scale;
                    const int b = m >> 11, tt = m & (T_ - 1);
                    const int h = nw >> 6, hd = nw & 63;
                    outp[((size_t)((b * H_ + h) * T_ + tt)) * HD_ + hd] = (bf16)val;
                }
    } else {
        #pragma unroll
        for (int i = 0; i < 8; ++i)
            #pragma unroll
            for (int j = 0; j < 4; ++j)
                #pragma unroll
                for (int r = 0; r < 4; ++r) {
                    const int d = mbase + wr * 128 + i * 16 + lg * 4 + r;    // 0..1023
                    const int n = nbase + wc * 64 + j * 16 + lr;             // token
                    const int b = n >> 11, tt = n & (T_ - 1);
                    outp[((size_t)(b * D_ + d)) * T_ + tt] = (bf16)(acc[i][j][r] + bias[d]);
                }
    }
}

// ========= out projection: BM=64 x BN=128 tiles, 512 blocks (2/CU), fp32 out =========
__global__ __launch_bounds__(256, 2) void gemm_out_kernel(
    const bf16* __restrict__ A, const bf16* __restrict__ WoT,
    const float* __restrict__ bo, float* __restrict__ Out)
{
    constexpr int K = D_;
    constexpr int NK = K / 64;
    __shared__ bf16 As[2][64][64];    // 16 KB
    __shared__ bf16 Bs[2][128][64];   // 32 KB

    const int bid = blockIdx.x;
    const int swz = (bid & 7) * 64 + (bid >> 3);   // XCD-bijective (512 % 8 == 0)
    const int m0 = (swz & 63) * 64, n0 = (swz >> 6) * 128;

    const int tid = threadIdx.x, wave = tid >> 6, lane = tid & 63;
    const int l5 = lane & 31, hi = lane >> 5;
    const int rseg = lane >> 3;
    const int srcc = (lane & 7) ^ rseg;

    auto stage = [&](int b, int k0) {
        #pragma unroll
        for (int cc = 0; cc < 2; ++cc) {       // A: 8 segs, 2/wave
            const int seg = wave * 2 + cc;
            const int row = seg * 8 + rseg;
            GLOAD_LDS(A + (size_t)(m0 + row) * K + k0 + srcc * 8, &As[b][seg * 8][0]);
        }
        #pragma unroll
        for (int cc = 0; cc < 4; ++cc) {       // B: 16 segs, 4/wave
            const int seg = wave * 4 + cc;
            const int row = seg * 8 + rseg;
            GLOAD_LDS(WoT + (size_t)(n0 + row) * K + k0 + srcc * 8, &Bs[b][seg * 8][0]);
        }
    };

    f32x16 acc[2] = {};
    stage(0, 0);
    __syncthreads();

    #pragma unroll 1
    for (int t = 0; t < NK; ++t) {
        const int cur = t & 1;
        if (t + 1 < NK) stage(cur ^ 1, (t + 1) * 64);

        bf16x8 af[2][4], bfr[4];
        #pragma unroll
        for (int mi = 0; mi < 2; ++mi)
            #pragma unroll
            for (int ks = 0; ks < 4; ++ks) {
                const int row = mi * 32 + l5;
                af[mi][ks] = *reinterpret_cast<const bf16x8*>(
                    &As[cur][row][((ks * 2 + hi) ^ (row & 7)) * 8]);
            }
        #pragma unroll
        for (int ks = 0; ks < 4; ++ks) {
            const int row = wave * 32 + l5;
            bfr[ks] = *reinterpret_cast<const bf16x8*>(
                &Bs[cur][row][((ks * 2 + hi) ^ (row & 7)) * 8]);
        }
        __builtin_amdgcn_s_setprio(1);
        #pragma unroll
        for (int mi = 0; mi < 2; ++mi)
            #pragma unroll
            for (int ks = 0; ks < 4; ++ks)
                acc[mi] = __builtin_amdgcn_mfma_f32_32x32x16_bf16(
                    af[mi][ks], bfr[ks], acc[mi], 0, 0, 0);
        __builtin_amdgcn_s_setprio(0);
        __syncthreads();
    }

    #pragma unroll
    for (int mi = 0; mi < 2; ++mi)
        #pragma unroll
        for (int q = 0; q < 16; ++q) {
            const int m = m0 + mi * 32 + (q & 3) + 8 * (q >> 2) + 4 * hi;
            const int n = n0 + wave * 32 + l5;
            Out[(size_t)m * D_ + n] = acc[mi][q] + bo[n];
        }
}

// ======= flash attention: QBLK=64, 4 waves, 512 paired blocks (2/CU), XCD-grouped =======
__global__ __launch_bounds__(256) void attn_kernel(
    const bf16* __restrict__ Q, const bf16* __restrict__ K,
    const bf16* __restrict__ Vt, bf16* __restrict__ Out)
{
    const int bid = blockIdx.x;
    const int xcd = bid & 7, j = bid >> 3;       // j 0..63
    const int bh  = xcd * 4 + (j >> 4);          // 4 bh per XCD
    const int pr  = j & 15;                      // pair index 0..15

    const int tid = threadIdx.x, wave = tid >> 6, lane = tid & 63;  // 4 waves
    const int lr = lane & 15, lg = lane >> 4;
    const size_t kbase = (size_t)bh * T_ * HD_;   // Q,K
    const size_t vbase = (size_t)bh * HD_ * T_;   // Vt

    __shared__ bf16 Ks[2][64][64];   // 16 KB
    __shared__ bf16 Vs[2][64][64];   // 16 KB  (Vs[buf][d][key])
    __shared__ bf16 Ps[4][16][72];   // 9 KB   per-wave P[q][key], padded

    auto stage = [&](int sb, int kt) {
        const int kv0 = kt * 64;
        const int rseg = lane >> 3;
        const int srcw = (lane & 7) ^ rseg;      // XOR source-chunk swizzle (involution)
        #pragma unroll
        for (int cc = 0; cc < 2; ++cc) {
            const int seg = wave * 2 + cc;       // 0..7
            const int row = seg * 8 + rseg;      // 0..63
            GLOAD_LDS(K  + kbase + (size_t)(kv0 + row) * HD_ + srcw * 8, &Ks[sb][seg * 8][0]);
            GLOAD_LDS(Vt + vbase + (size_t)row * T_ + kv0 + srcw * 8,    &Vs[sb][seg * 8][0]);
        }
    };
    auto kfrag = [&](int sb, int row, int chunk) {
        return *reinterpret_cast<const bf16x8*>(&Ks[sb][row][(chunk ^ (row & 7)) * 8]);
    };
    auto vfrag = [&](int sb, int row, int chunk) {
        return *reinterpret_cast<const bf16x8*>(&Vs[sb][row][(chunk ^ (row & 7)) * 8]);
    };

    #pragma unroll 1
    for (int half = 0; half < 2; ++half) {
        const int qb = half == 0 ? pr : (NQB - 1 - pr);
        const int q0 = qb * 64;
        const int nt = qb + 1;                   // tiles 0..qb (all active)
        const int qw = wave * 16;

        // Q fragments for this wave's 16 rows (B-operand: col=lane&15 -> q=lr)
        bf16x8 qf[2];
        {
            const bf16* qrow = Q + kbase + (size_t)(q0 + qw + lr) * HD_;
            qf[0] = *reinterpret_cast<const bf16x8*>(qrow + lg * 8);
            qf[1] = *reinterpret_cast<const bf16x8*>(qrow + 32 + lg * 8);
        }

        float m_s = -1e30f, l_s = 0.f;           // log2-domain state for q = q0+qw+lr
        f32x4 o_acc[4] = {};                     // O[q=qw+lg*4+r][d=nd*16+lr]

        stage(0, 0);
        __syncthreads();

        #pragma unroll 1
        for (int t = 0; t < nt; ++t) {
            const int cur = t & 1;
            if (t + 1 < nt) stage(cur ^ 1, t + 1);   // prefetch next tile

            const int kv0 = t * 64;
            // S'[key][q]: key = kv0 + n16*16 + lg*4 + r, q = q0 + qw + lr
            f32x4 s[4] = {};
            __builtin_amdgcn_s_setprio(1);
            #pragma unroll
            for (int n16 = 0; n16 < 4; ++n16)
                #pragma unroll
                for (int kk = 0; kk < 2; ++kk)
                    s[n16] = __builtin_amdgcn_mfma_f32_16x16x32_bf16(
                        kfrag(cur, n16 * 16 + lr, kk * 4 + lg), qf[kk], s[n16], 0, 0, 0);
            __builtin_amdgcn_s_setprio(0);
            if (t == qb) {                       // causal mask on diagonal tile
                #pragma unroll
                for (int n16 = 0; n16 < 4; ++n16)
                    #pragma unroll
                    for (int r = 0; r < 4; ++r)
                        if (kv0 + n16 * 16 + lg * 4 + r > q0 + qw + lr)
                            s[n16][r] = -1e30f;
            }
            // online softmax, log2 domain, defer-max (8 nats = 11.54 bits)
            float mx = s[0][0];
            #pragma unroll
            for (int n16 = 0; n16 < 4; ++n16)
                #pragma unroll
                for (int r = 0; r < 4; ++r)
                    mx = fmaxf(mx, s[n16][r]);
            mx = fmaxf(mx, __shfl_xor(mx, 16));
            mx = fmaxf(mx, __shfl_xor(mx, 32));
            if (__any(mx > m_s + 11.5416f)) {
                const float mnew  = fmaxf(m_s, mx);
                const float alpha = exp2_fast(m_s - mnew);
                #pragma unroll
                for (int r = 0; r < 4; ++r) {
                    const float a = __shfl(alpha, lg * 4 + r);
                    #pragma unroll
                    for (int nd = 0; nd < 4; ++nd) o_acc[nd][r] *= a;
                }
                l_s *= alpha;
                m_s = mnew;
            }
            float rs = 0.f;
            #pragma unroll
            for (int n16 = 0; n16 < 4; ++n16) {
                bf16x4 pw;
                #pragma unroll
                for (int r = 0; r < 4; ++r) {
                    const float p = exp2_fast(s[n16][r] - m_s);   // bounded by 2^11.54
                    rs += p;
                    pw[r] = (bf16)p;
                }
                *reinterpret_cast<bf16x4*>(&Ps[wave][lr][n16 * 16 + lg * 4]) = pw;
            }
            rs += __shfl_xor(rs, 16);
            rs += __shfl_xor(rs, 32);
            l_s += rs;
            // O += P @ V
            __builtin_amdgcn_s_setprio(1);
            #pragma unroll
            for (int ks = 0; ks < 2; ++ks) {
                const bf16x8 pa = *reinterpret_cast<const bf16x8*>(&Ps[wave][lr][ks * 32 + lg * 8]);
                #pragma unroll
                for (int nd = 0; nd < 4; ++nd)
                    o_acc[nd] = __builtin_amdgcn_mfma_f32_16x16x32_bf16(
                        pa, vfrag(cur, nd * 16 + lr, ks * 4 + lg), o_acc[nd], 0, 0, 0);
            }
            __builtin_amdgcn_s_setprio(0);
            __syncthreads();   // all reads of cur done; next tile fully staged
        }

        // normalize + store to [b*T+t][h*64+d]
        const int b = bh >> 4, h = bh & 15;
        const float linv = 1.0f / l_s;
        #pragma unroll
        for (int r = 0; r < 4; ++r) {
            const float li = __shfl(linv, lg * 4 + r);
            const int q = q0 + qw + lg * 4 + r;
            #pragma unroll
            for (int nd = 0; nd < 4; ++nd) {
                const int d = nd * 16 + lr;
                Out[((size_t)(b * T_ + q)) * D_ + h * HD_ + d] = (bf16)(o_acc[nd][r] * li);
            }
        }
    }
}

// ---------------- launch ----------------
extern "C" void kernel_launch(void* const* d_in, const int* in_sizes, int n_in,
                              void* d_out, int out_size, void* d_ws, size_t ws_size,
                              hipStream_t stream) {
    const float* x  = (const float*)d_in[0];
    const float* Wq = (const float*)d_in[1];
    const float* bq = (const float*)d_in[2];
    const float* Wk = (const float*)d_in[3];
    const float* bk = (const float*)d_in[4];
    const float* Wv = (const float*)d_in[5];
    const float* bv = (const float*)d_in[6];
    const float* Wo = (const float*)d_in[7];
    const float* bo = (const float*)d_in[8];
    float* out = (float*)d_out;

    char* ws = (char*)d_ws;
    bf16* xb   = (bf16*)(ws);                         // 8 MB  [4096][1024]
    bf16* WqT  = (bf16*)(ws + ( 8u << 20));           // 2 MB  [1024][1024]
    bf16* WkT  = (bf16*)(ws + (10u << 20));
    bf16* WvT  = (bf16*)(ws + (12u << 20));
    bf16* WoT  = (bf16*)(ws + (14u << 20));
    bf16* Qb   = (bf16*)(ws + (16u << 20));           // 8 MB  [32][2048][64]
    bf16* Kb   = (bf16*)(ws + (24u << 20));
    bf16* Vtb  = (bf16*)(ws + (32u << 20));           // 8 MB  [32][64][2048]
    bf16* attn = (bf16*)(ws + (40u << 20));           // 8 MB  [4096][1024]

    prep_kernel<<<dim3(32, 32, 5), 256, 0, stream>>>(
        x, xb, Wq, WqT, Wk, WkT, Wv, WvT, Wo, WoT);

    qkv256_kernel<<<192, 512, 0, stream>>>(xb, WqT, bq, Qb, WkT, bk, Kb, WvT, bv, Vtb);

    attn_kernel<<<512, 256, 0, stream>>>(Qb, Kb, Vtb, attn);

    gemm_out_kernel<<<512, 256, 0, stream>>>(attn, WoT, bo, out);
}

// Round 21
// 107.948 us; speedup vs baseline: 1.3861x; 1.0309x over previous
//
#include <hip/hip_runtime.h>
#include <cstdint>
#include <cstddef>

typedef __bf16 bf16;
typedef __bf16 bf16x4 __attribute__((ext_vector_type(4)));
typedef __bf16 bf16x8 __attribute__((ext_vector_type(8)));
typedef float  f32x4  __attribute__((ext_vector_type(4)));
typedef float  f32x16 __attribute__((ext_vector_type(16)));

#define B_  2
#define T_  2048
#define D_  1024
#define H_  16
#define HD_ 64
#define M_  (B_ * T_)   // 4096 rows
#define NQB 32          // T_/64 q-blocks

#define GLOAD_LDS(gsrc, ldst) \
    __builtin_amdgcn_global_load_lds( \
        (const __attribute__((address_space(1))) void*)(gsrc), \
        (__attribute__((address_space(3))) void*)(ldst), 16, 0, 0)

// fast 2^x: single v_exp_f32 (ISA: D = 2^S0), no libm range handling
__device__ __forceinline__ float exp2_fast(float x) {
    float r;
    asm("v_exp_f32 %0, %1" : "=v"(r) : "v"(x));
    return r;
}

__device__ __forceinline__ void barrier_pin() {
    asm volatile("" ::: "memory");
    __builtin_amdgcn_s_barrier();
    asm volatile("" ::: "memory");
}

// ------- merged prologue: z<4 -> transpose+cast W_z; z==4 -> cast x -------
__global__ void prep_kernel(
    const float* __restrict__ x,  bf16* __restrict__ xb,
    const float* __restrict__ W0, bf16* __restrict__ T0,
    const float* __restrict__ W1, bf16* __restrict__ T1,
    const float* __restrict__ W2, bf16* __restrict__ T2,
    const float* __restrict__ W3, bf16* __restrict__ T3)
{
    if (blockIdx.z == 4) {
        const int linear = blockIdx.y * 32 + blockIdx.x;
        const int base = linear * 4096 + threadIdx.x * 4;
        #pragma unroll
        for (int u = 0; u < 4; ++u) {
            const int i = base + u * 1024;
            const float4 v = *reinterpret_cast<const float4*>(x + i);
            bf16x4 o = { (bf16)v.x, (bf16)v.y, (bf16)v.z, (bf16)v.w };
            *reinterpret_cast<bf16x4*>(xb + i) = o;
        }
        return;
    }
    __shared__ float tile[32][33];
    const float* W = blockIdx.z == 0 ? W0 : blockIdx.z == 1 ? W1 : blockIdx.z == 2 ? W2 : W3;
    bf16*       Wt = blockIdx.z == 0 ? T0 : blockIdx.z == 1 ? T1 : blockIdx.z == 2 ? T2 : T3;
    const int tx = threadIdx.x & 31, ty = threadIdx.x >> 5;  // 32 x 8
    const int bx = blockIdx.x * 32, by = blockIdx.y * 32;
    #pragma unroll
    for (int r = 0; r < 32; r += 8)
        tile[ty + r][tx] = W[(size_t)(by + ty + r) * D_ + bx + tx];
    __syncthreads();
    #pragma unroll
    for (int r = 0; r < 32; r += 8)
        Wt[(size_t)(bx + ty + r) * D_ + by + tx] = (bf16)tile[tx][ty + r];
}

// ================= 256x256 8-phase QKV kernel (T2+T3+T4+T5) =================
// Per tile t (buffer c): p0 {LDA0,LDB0 | stage A[cn][1](t+1)} -> quad(A0,B0)
//                        p1 {LDB1      | stage B[cn][0](t+1)} -> quad(A0,B1)
//                        p2 {LDA1      | stage A[c ][0](t+2)} -> quad(A1,B1)
//                        p3 {          | stage B[c ][1](t+2); vmcnt(4)} -> quad(A1,B0)
__global__ __launch_bounds__(512, 2) void qkv256_kernel(
    const bf16* __restrict__ xb,
    const bf16* __restrict__ WqT, const float* __restrict__ bq, bf16* __restrict__ Qo,
    const bf16* __restrict__ WkT, const float* __restrict__ bk, bf16* __restrict__ Ko,
    const bf16* __restrict__ WvT, const float* __restrict__ bv, bf16* __restrict__ Vt)
{
    __shared__ bf16 As[2][2][128][64];   // 64 KiB
    __shared__ bf16 Bs[2][2][128][64];   // 64 KiB

    const int bid = blockIdx.x;
    const int swz = (bid & 7) * 24 + (bid >> 3);       // XCD-bijective (192 % 8 == 0)
    const int tid = threadIdx.x, wave = tid >> 6, lane = tid & 63;
    const int lr = lane & 15, lg = lane >> 4;
    const int wr = wave >> 2, wc = wave & 3;

    const bf16 *Aop, *Bop;
    const float *bias;
    bf16 *outp;
    float scale = 1.0f;
    int mbase, nbase, mode;
    if (swz < 128) {
        const int bm = swz >> 3, bn = swz & 7;
        mbase = bm * 256;                               // token rows
        nbase = (bn & 3) * 256;                         // col within Wq or Wk
        Aop = xb + (size_t)mbase * D_;
        if (bn < 4) { Bop = WqT + (size_t)nbase * D_; bias = bq; outp = Qo;
                      scale = 0.125f * 1.44269504f; }   // log2e folded for exp2 softmax
        else        { Bop = WkT + (size_t)nbase * D_; bias = bk; outp = Ko; }
        mode = 0;
    } else {
        const int v = swz - 128, bm = v >> 4, bn = v & 15;
        mbase = bm * 256;                               // d rows
        nbase = bn * 256;                               // token cols
        Aop = WvT + (size_t)mbase * D_;
        Bop = xb  + (size_t)nbase * D_;
        bias = bv; outp = Vt; mode = 1;
    }

    // ---- staging: one half-tile = 2 gload_lds per wave; XOR source-chunk swizzle ----
    const int r8   = lane >> 3;
    const int srcc = (lane & 7) ^ r8;
    auto stageA = [&](int c, int h, int kt) {
        #pragma unroll
        for (int l = 0; l < 2; ++l) {
            const int cr  = wave * 2 + l;
            const int loc = cr * 8 + r8;                            // 0..127
            const int rho = h * 64 + (loc & 63) + ((loc >> 6) << 7); // stripe map
            GLOAD_LDS(Aop + (size_t)rho * D_ + kt * 64 + srcc * 8, &As[c][h][cr * 8][0]);
        }
    };
    auto stageB = [&](int c, int h, int kt) {
        #pragma unroll
        for (int l = 0; l < 2; ++l) {
            const int cr  = wave * 2 + l;
            const int loc = cr * 8 + r8;
            const int rho = h * 32 + (loc & 31) + ((loc >> 5) << 6);
            GLOAD_LDS(Bop + (size_t)rho * D_ + kt * 64 + srcc * 8, &Bs[c][h][cr * 8][0]);
        }
    };

    f32x4 acc[8][4] = {};
    bf16x8 ar[4][2], b0r[2][2], b1r[2][2];

    auto LDA = [&](int c, int mh) {
        #pragma unroll
        for (int i = 0; i < 4; ++i)
            #pragma unroll
            for (int kk = 0; kk < 2; ++kk)
                ar[i][kk] = *reinterpret_cast<const bf16x8*>(
                    &As[c][mh][wr * 64 + i * 16 + lr][(((kk * 4 + lg)) ^ (lr & 7)) * 8]);
    };
    auto LDB = [&](int c, int nh, bf16x8 (&br)[2][2]) {
        #pragma unroll
        for (int j = 0; j < 2; ++j)
            #pragma unroll
            for (int kk = 0; kk < 2; ++kk)
                br[j][kk] = *reinterpret_cast<const bf16x8*>(
                    &Bs[c][nh][wc * 32 + j * 16 + lr][(((kk * 4 + lg)) ^ (lr & 7)) * 8]);
    };
    auto QUAD = [&](const bf16x8 (&br)[2][2], int mh, int nh) {
        __builtin_amdgcn_s_setprio(1);
        #pragma unroll
        for (int i = 0; i < 4; ++i)
            #pragma unroll
            for (int j = 0; j < 2; ++j)
                #pragma unroll
                for (int kk = 0; kk < 2; ++kk)
                    acc[mh * 4 + i][nh * 2 + j] = __builtin_amdgcn_mfma_f32_16x16x32_bf16(
                        ar[i][kk], br[j][kk], acc[mh * 4 + i][nh * 2 + j], 0, 0, 0);
        __builtin_amdgcn_s_setprio(0);
    };

    constexpr int NK = D_ / 64;   // 16 K-tiles
    // prologue: tile0 all 4 halves + tile1's {A0, B1}
    stageA(0, 0, 0); stageB(0, 0, 0); stageA(0, 1, 0); stageB(0, 1, 0);
    stageA(1, 0, 1); stageB(1, 1, 1);
    asm volatile("s_waitcnt vmcnt(4)" ::: "memory");   // tile0 resident; t1's 2 stages in flight
    barrier_pin();

    #pragma unroll 1
    for (int t = 0; t < NK; ++t) {
        const int c = t & 1, cn = c ^ 1;
        const bool h1 = (t + 1 < NK), h2 = (t + 2 < NK);
        // ---- phase 0: quad (A0,B0); reads BEFORE barrier ----
        LDA(c, 0); LDB(c, 0, b0r);
        if (h1) stageA(cn, 1, t + 1);
        barrier_pin();
        QUAD(b0r, 0, 0);
        barrier_pin();
        // ---- phase 1: quad (A0,B1) ----
        LDB(c, 1, b1r);
        if (h1) stageB(cn, 0, t + 1);
        barrier_pin();
        QUAD(b1r, 0, 1);
        barrier_pin();
        // ---- phase 2: quad (A1,B1) ----
        LDA(c, 1);
        if (h2) stageA(c, 0, t + 2);     // A[c][0] dead since p0 (in regs)
        barrier_pin();
        QUAD(b1r, 1, 1);
        barrier_pin();
        // ---- phase 3: quad (A1,B0); B0 still in regs from p0 ----
        if (h2) stageB(c, 1, t + 2);     // B[c][1] dead since p1 (in regs)
        asm volatile("s_waitcnt vmcnt(4)" ::: "memory");   // tile t+1 fully resident
        barrier_pin();
        QUAD(b0r, 1, 0);
        barrier_pin();
    }

    // ---- epilogue ----
    if (mode == 0) {
        #pragma unroll
        for (int i = 0; i < 8; ++i)
            #pragma unroll
            for (int j = 0; j < 4; ++j)
                #pragma unroll
                for (int r = 0; r < 4; ++r) {
                    const int m  = mbase + wr * 128 + i * 16 + lg * 4 + r;   // token
                    const int nw = nbase + wc * 64 + j * 16 + lr;            // 0..1023
                    const float val = (acc[i][j][r] + bias[nw]) * scale;
                    const int b = m >> 11, tt = m & (T_ - 1);
                    const int h = nw >> 6, hd = nw & 63;
                    outp[((size_t)((b * H_ + h) * T_ + tt)) * HD_ + hd] = (bf16)val;
                }
    } else {
        #pragma unroll
        for (int i = 0; i < 8; ++i)
            #pragma unroll
            for (int j = 0; j < 4; ++j)
                #pragma unroll
                for (int r = 0; r < 4; ++r) {
                    const int d = mbase + wr * 128 + i * 16 + lg * 4 + r;    // 0..1023
                    const int n = nbase + wc * 64 + j * 16 + lr;             // token
                    const int b = n >> 11, tt = n & (T_ - 1);
                    outp[((size_t)(b * D_ + d)) * T_ + tt] = (bf16)(acc[i][j][r] + bias[d]);
                }
    }
}

// ========= out projection: BM=64 x BN=128 tiles, 512 blocks (2/CU), fp32 out =========
__global__ __launch_bounds__(256, 2) void gemm_out_kernel(
    const bf16* __restrict__ A, const bf16* __restrict__ WoT,
    const float* __restrict__ bo, float* __restrict__ Out)
{
    constexpr int K = D_;
    constexpr int NK = K / 64;
    __shared__ bf16 As[2][64][64];    // 16 KB
    __shared__ bf16 Bs[2][128][64];   // 32 KB

    const int bid = blockIdx.x;
    const int swz = (bid & 7) * 64 + (bid >> 3);   // XCD-bijective (512 % 8 == 0)
    const int m0 = (swz & 63) * 64, n0 = (swz >> 6) * 128;

    const int tid = threadIdx.x, wave = tid >> 6, lane = tid & 63;
    const int l5 = lane & 31, hi = lane >> 5;
    const int rseg = lane >> 3;
    const int srcc = (lane & 7) ^ rseg;

    auto stage = [&](int b, int k0) {
        #pragma unroll
        for (int cc = 0; cc < 2; ++cc) {       // A: 8 segs, 2/wave
            const int seg = wave * 2 + cc;
            const int row = seg * 8 + rseg;
            GLOAD_LDS(A + (size_t)(m0 + row) * K + k0 + srcc * 8, &As[b][seg * 8][0]);
        }
        #pragma unroll
        for (int cc = 0; cc < 4; ++cc) {       // B: 16 segs, 4/wave
            const int seg = wave * 4 + cc;
            const int row = seg * 8 + rseg;
            GLOAD_LDS(WoT + (size_t)(n0 + row) * K + k0 + srcc * 8, &Bs[b][seg * 8][0]);
        }
    };

    f32x16 acc[2] = {};
    stage(0, 0);
    __syncthreads();

    #pragma unroll 1
    for (int t = 0; t < NK; ++t) {
        const int cur = t & 1;
        if (t + 1 < NK) stage(cur ^ 1, (t + 1) * 64);

        bf16x8 af[2][4], bfr[4];
        #pragma unroll
        for (int mi = 0; mi < 2; ++mi)
            #pragma unroll
            for (int ks = 0; ks < 4; ++ks) {
                const int row = mi * 32 + l5;
                af[mi][ks] = *reinterpret_cast<const bf16x8*>(
                    &As[cur][row][((ks * 2 + hi) ^ (row & 7)) * 8]);
            }
        #pragma unroll
        for (int ks = 0; ks < 4; ++ks) {
            const int row = wave * 32 + l5;
            bfr[ks] = *reinterpret_cast<const bf16x8*>(
                &Bs[cur][row][((ks * 2 + hi) ^ (row & 7)) * 8]);
        }
        __builtin_amdgcn_s_setprio(1);
        #pragma unroll
        for (int mi = 0; mi < 2; ++mi)
            #pragma unroll
            for (int ks = 0; ks < 4; ++ks)
                acc[mi] = __builtin_amdgcn_mfma_f32_32x32x16_bf16(
                    af[mi][ks], bfr[ks], acc[mi], 0, 0, 0);
        __builtin_amdgcn_s_setprio(0);
        __syncthreads();
    }

    #pragma unroll
    for (int mi = 0; mi < 2; ++mi)
        #pragma unroll
        for (int q = 0; q < 16; ++q) {
            const int m = m0 + mi * 32 + (q & 3) + 8 * (q >> 2) + 4 * hi;
            const int n = n0 + wave * 32 + l5;
            Out[(size_t)m * D_ + n] = acc[mi][q] + bo[n];
        }
}

// ======= flash attention: QBLK=64, 4 waves, 512 paired blocks (2/CU), XCD-grouped =======
// Cheap defer-check: __any over LANE-LOCAL max (cross-lane OR is what __any does);
// the full row-max reduce (2 shfl) only runs in the rare rescale branch.
__global__ __launch_bounds__(256) void attn_kernel(
    const bf16* __restrict__ Q, const bf16* __restrict__ K,
    const bf16* __restrict__ Vt, bf16* __restrict__ Out)
{
    const int bid = blockIdx.x;
    const int xcd = bid & 7, j = bid >> 3;       // j 0..63
    const int bh  = xcd * 4 + (j >> 4);          // 4 bh per XCD
    const int pr  = j & 15;                      // pair index 0..15

    const int tid = threadIdx.x, wave = tid >> 6, lane = tid & 63;  // 4 waves
    const int lr = lane & 15, lg = lane >> 4;
    const size_t kbase = (size_t)bh * T_ * HD_;   // Q,K
    const size_t vbase = (size_t)bh * HD_ * T_;   // Vt

    __shared__ bf16 Ks[2][64][64];   // 16 KB
    __shared__ bf16 Vs[2][64][64];   // 16 KB  (Vs[buf][d][key])
    __shared__ bf16 Ps[4][16][72];   // 9 KB   per-wave P[q][key], padded

    auto stage = [&](int sb, int kt) {
        const int kv0 = kt * 64;
        const int rseg = lane >> 3;
        const int srcw = (lane & 7) ^ rseg;      // XOR source-chunk swizzle (involution)
        #pragma unroll
        for (int cc = 0; cc < 2; ++cc) {
            const int seg = wave * 2 + cc;       // 0..7
            const int row = seg * 8 + rseg;      // 0..63
            GLOAD_LDS(K  + kbase + (size_t)(kv0 + row) * HD_ + srcw * 8, &Ks[sb][seg * 8][0]);
            GLOAD_LDS(Vt + vbase + (size_t)row * T_ + kv0 + srcw * 8,    &Vs[sb][seg * 8][0]);
        }
    };
    auto kfrag = [&](int sb, int row, int chunk) {
        return *reinterpret_cast<const bf16x8*>(&Ks[sb][row][(chunk ^ (row & 7)) * 8]);
    };
    auto vfrag = [&](int sb, int row, int chunk) {
        return *reinterpret_cast<const bf16x8*>(&Vs[sb][row][(chunk ^ (row & 7)) * 8]);
    };

    #pragma unroll 1
    for (int half = 0; half < 2; ++half) {
        const int qb = half == 0 ? pr : (NQB - 1 - pr);
        const int q0 = qb * 64;
        const int nt = qb + 1;                   // tiles 0..qb (all active)
        const int qw = wave * 16;

        // Q fragments for this wave's 16 rows (B-operand: col=lane&15 -> q=lr)
        bf16x8 qf[2];
        {
            const bf16* qrow = Q + kbase + (size_t)(q0 + qw + lr) * HD_;
            qf[0] = *reinterpret_cast<const bf16x8*>(qrow + lg * 8);
            qf[1] = *reinterpret_cast<const bf16x8*>(qrow + 32 + lg * 8);
        }

        float m_s = -1e30f, l_s = 0.f;           // log2-domain state for q = q0+qw+lr
        f32x4 o_acc[4] = {};                     // O[q=qw+lg*4+r][d=nd*16+lr]

        stage(0, 0);
        __syncthreads();

        #pragma unroll 1
        for (int t = 0; t < nt; ++t) {
            const int cur = t & 1;
            if (t + 1 < nt) stage(cur ^ 1, t + 1);   // prefetch next tile

            const int kv0 = t * 64;
            // S'[key][q]: key = kv0 + n16*16 + lg*4 + r, q = q0 + qw + lr
            f32x4 s[4] = {};
            __builtin_amdgcn_s_setprio(1);
            #pragma unroll
            for (int n16 = 0; n16 < 4; ++n16)
                #pragma unroll
                for (int kk = 0; kk < 2; ++kk)
                    s[n16] = __builtin_amdgcn_mfma_f32_16x16x32_bf16(
                        kfrag(cur, n16 * 16 + lr, kk * 4 + lg), qf[kk], s[n16], 0, 0, 0);
            __builtin_amdgcn_s_setprio(0);
            if (t == qb) {                       // causal mask on diagonal tile
                #pragma unroll
                for (int n16 = 0; n16 < 4; ++n16)
                    #pragma unroll
                    for (int r = 0; r < 4; ++r)
                        if (kv0 + n16 * 16 + lg * 4 + r > q0 + qw + lr)
                            s[n16][r] = -1e30f;
            }
            // online softmax, log2 domain, defer-max (8 nats = 11.54 bits)
            float mx = s[0][0];                  // lane-local 16-value max
            #pragma unroll
            for (int n16 = 0; n16 < 4; ++n16)
                #pragma unroll
                for (int r = 0; r < 4; ++r)
                    mx = fmaxf(mx, s[n16][r]);
            if (__any(mx > m_s + 11.5416f)) {    // rare: full row-max + rescale
                mx = fmaxf(mx, __shfl_xor(mx, 16));
                mx = fmaxf(mx, __shfl_xor(mx, 32));
                const float mnew  = fmaxf(m_s, mx);
                const float alpha = exp2_fast(m_s - mnew);
                #pragma unroll
                for (int r = 0; r < 4; ++r) {
                    const float a = __shfl(alpha, lg * 4 + r);
                    #pragma unroll
                    for (int nd = 0; nd < 4; ++nd) o_acc[nd][r] *= a;
                }
                l_s *= alpha;
                m_s = mnew;
            }
            float rs = 0.f;
            #pragma unroll
            for (int n16 = 0; n16 < 4; ++n16) {
                bf16x4 pw;
                #pragma unroll
                for (int r = 0; r < 4; ++r) {
                    const float p = exp2_fast(s[n16][r] - m_s);   // bounded by 2^11.54
                    rs += p;
                    pw[r] = (bf16)p;
                }
                *reinterpret_cast<bf16x4*>(&Ps[wave][lr][n16 * 16 + lg * 4]) = pw;
            }
            rs += __shfl_xor(rs, 16);
            rs += __shfl_xor(rs, 32);
            l_s += rs;
            // O += P @ V
            __builtin_amdgcn_s_setprio(1);
            #pragma unroll
            for (int ks = 0; ks < 2; ++ks) {
                const bf16x8 pa = *reinterpret_cast<const bf16x8*>(&Ps[wave][lr][ks * 32 + lg * 8]);
                #pragma unroll
                for (int nd = 0; nd < 4; ++nd)
                    o_acc[nd] = __builtin_amdgcn_mfma_f32_16x16x32_bf16(
                        pa, vfrag(cur, nd * 16 + lr, ks * 4 + lg), o_acc[nd], 0, 0, 0);
            }
            __builtin_amdgcn_s_setprio(0);
            __syncthreads();   // all reads of cur done; next tile fully staged
        }

        // normalize + store to [b*T+t][h*64+d]
        const int b = bh >> 4, h = bh & 15;
        const float linv = 1.0f / l_s;
        #pragma unroll
        for (int r = 0; r < 4; ++r) {
            const float li = __shfl(linv, lg * 4 + r);
            const int q = q0 + qw + lg * 4 + r;
            #pragma unroll
            for (int nd = 0; nd < 4; ++nd) {
                const int d = nd * 16 + lr;
                Out[((size_t)(b * T_ + q)) * D_ + h * HD_ + d] = (bf16)(o_acc[nd][r] * li);
            }
        }
    }
}

// ---------------- launch ----------------
extern "C" void kernel_launch(void* const* d_in, const int* in_sizes, int n_in,
                              void* d_out, int out_size, void* d_ws, size_t ws_size,
                              hipStream_t stream) {
    const float* x  = (const float*)d_in[0];
    const float* Wq = (const float*)d_in[1];
    const float* bq = (const float*)d_in[2];
    const float* Wk = (const float*)d_in[3];
    const float* bk = (const float*)d_in[4];
    const float* Wv = (const float*)d_in[5];
    const float* bv = (const float*)d_in[6];
    const float* Wo = (const float*)d_in[7];
    const float* bo = (const float*)d_in[8];
    float* out = (float*)d_out;

    char* ws = (char*)d_ws;
    bf16* xb   = (bf16*)(ws);                         // 8 MB  [4096][1024]
    bf16* WqT  = (bf16*)(ws + ( 8u << 20));           // 2 MB  [1024][1024]
    bf16* WkT  = (bf16*)(ws + (10u << 20));
    bf16* WvT  = (bf16*)(ws + (12u << 20));
    bf16* WoT  = (bf16*)(ws + (14u << 20));
    bf16* Qb   = (bf16*)(ws + (16u << 20));           // 8 MB  [32][2048][64]
    bf16* Kb   = (bf16*)(ws + (24u << 20));
    bf16* Vtb  = (bf16*)(ws + (32u << 20));           // 8 MB  [32][64][2048]
    bf16* attn = (bf16*)(ws + (40u << 20));           // 8 MB  [4096][1024]

    prep_kernel<<<dim3(32, 32, 5), 256, 0, stream>>>(
        x, xb, Wq, WqT, Wk, WkT, Wv, WvT, Wo, WoT);

    qkv256_kernel<<<192, 512, 0, stream>>>(xb, WqT, bq, Qb, WkT, bk, Kb, WvT, bv, Vtb);

    attn_kernel<<<512, 256, 0, stream>>>(Qb, Kb, Vtb, attn);

    gemm_out_kernel<<<512, 256, 0, stream>>>(attn, WoT, bo, out);
}

// Round 22
// 106.063 us; speedup vs baseline: 1.4108x; 1.0178x over previous
//
#include <hip/hip_runtime.h>
#include <cstdint>
#include <cstddef>

typedef __bf16 bf16;
typedef __bf16 bf16x4 __attribute__((ext_vector_type(4)));
typedef __bf16 bf16x8 __attribute__((ext_vector_type(8)));
typedef float  f32x4  __attribute__((ext_vector_type(4)));
typedef float  f32x16 __attribute__((ext_vector_type(16)));

#define B_  2
#define T_  2048
#define D_  1024
#define H_  16
#define HD_ 64
#define M_  (B_ * T_)   // 4096 rows
#define NQB 32          // T_/64 q-blocks

#define GLOAD_LDS(gsrc, ldst) \
    __builtin_amdgcn_global_load_lds( \
        (const __attribute__((address_space(1))) void*)(gsrc), \
        (__attribute__((address_space(3))) void*)(ldst), 16, 0, 0)

// fast 2^x: single v_exp_f32 (ISA: D = 2^S0), no libm range handling
__device__ __forceinline__ float exp2_fast(float x) {
    float r;
    asm("v_exp_f32 %0, %1" : "=v"(r) : "v"(x));
    return r;
}

__device__ __forceinline__ void barrier_pin() {
    asm volatile("" ::: "memory");
    __builtin_amdgcn_s_barrier();
    asm volatile("" ::: "memory");
}

// ------- merged prologue: z<4 -> transpose+cast W_z; z==4 -> cast x -------
__global__ void prep_kernel(
    const float* __restrict__ x,  bf16* __restrict__ xb,
    const float* __restrict__ W0, bf16* __restrict__ T0,
    const float* __restrict__ W1, bf16* __restrict__ T1,
    const float* __restrict__ W2, bf16* __restrict__ T2,
    const float* __restrict__ W3, bf16* __restrict__ T3)
{
    if (blockIdx.z == 4) {
        const int linear = blockIdx.y * 32 + blockIdx.x;
        const int base = linear * 4096 + threadIdx.x * 4;
        #pragma unroll
        for (int u = 0; u < 4; ++u) {
            const int i = base + u * 1024;
            const float4 v = *reinterpret_cast<const float4*>(x + i);
            bf16x4 o = { (bf16)v.x, (bf16)v.y, (bf16)v.z, (bf16)v.w };
            *reinterpret_cast<bf16x4*>(xb + i) = o;
        }
        return;
    }
    __shared__ float tile[32][33];
    const float* W = blockIdx.z == 0 ? W0 : blockIdx.z == 1 ? W1 : blockIdx.z == 2 ? W2 : W3;
    bf16*       Wt = blockIdx.z == 0 ? T0 : blockIdx.z == 1 ? T1 : blockIdx.z == 2 ? T2 : T3;
    const int tx = threadIdx.x & 31, ty = threadIdx.x >> 5;  // 32 x 8
    const int bx = blockIdx.x * 32, by = blockIdx.y * 32;
    #pragma unroll
    for (int r = 0; r < 32; r += 8)
        tile[ty + r][tx] = W[(size_t)(by + ty + r) * D_ + bx + tx];
    __syncthreads();
    #pragma unroll
    for (int r = 0; r < 32; r += 8)
        Wt[(size_t)(bx + ty + r) * D_ + by + tx] = (bf16)tile[tx][ty + r];
}

// ================= 256x256 8-phase QKV kernel (T2+T3+T4+T5) =================
__global__ __launch_bounds__(512, 2) void qkv256_kernel(
    const bf16* __restrict__ xb,
    const bf16* __restrict__ WqT, const float* __restrict__ bq, bf16* __restrict__ Qo,
    const bf16* __restrict__ WkT, const float* __restrict__ bk, bf16* __restrict__ Ko,
    const bf16* __restrict__ WvT, const float* __restrict__ bv, bf16* __restrict__ Vt)
{
    __shared__ bf16 As[2][2][128][64];   // 64 KiB
    __shared__ bf16 Bs[2][2][128][64];   // 64 KiB

    const int bid = blockIdx.x;
    const int swz = (bid & 7) * 24 + (bid >> 3);       // XCD-bijective (192 % 8 == 0)
    const int tid = threadIdx.x, wave = tid >> 6, lane = tid & 63;
    const int lr = lane & 15, lg = lane >> 4;
    const int wr = wave >> 2, wc = wave & 3;

    const bf16 *Aop, *Bop;
    const float *bias;
    bf16 *outp;
    float scale = 1.0f;
    int mbase, nbase, mode;
    if (swz < 128) {
        const int bm = swz >> 3, bn = swz & 7;
        mbase = bm * 256;                               // token rows
        nbase = (bn & 3) * 256;                         // col within Wq or Wk
        Aop = xb + (size_t)mbase * D_;
        if (bn < 4) { Bop = WqT + (size_t)nbase * D_; bias = bq; outp = Qo;
                      scale = 0.125f * 1.44269504f; }   // log2e folded for exp2 softmax
        else        { Bop = WkT + (size_t)nbase * D_; bias = bk; outp = Ko; }
        mode = 0;
    } else {
        const int v = swz - 128, bm = v >> 4, bn = v & 15;
        mbase = bm * 256;                               // d rows
        nbase = bn * 256;                               // token cols
        Aop = WvT + (size_t)mbase * D_;
        Bop = xb  + (size_t)nbase * D_;
        bias = bv; outp = Vt; mode = 1;
    }

    // ---- staging: one half-tile = 2 gload_lds per wave; XOR source-chunk swizzle ----
    const int r8   = lane >> 3;
    const int srcc = (lane & 7) ^ r8;
    auto stageA = [&](int c, int h, int kt) {
        #pragma unroll
        for (int l = 0; l < 2; ++l) {
            const int cr  = wave * 2 + l;
            const int loc = cr * 8 + r8;                            // 0..127
            const int rho = h * 64 + (loc & 63) + ((loc >> 6) << 7); // stripe map
            GLOAD_LDS(Aop + (size_t)rho * D_ + kt * 64 + srcc * 8, &As[c][h][cr * 8][0]);
        }
    };
    auto stageB = [&](int c, int h, int kt) {
        #pragma unroll
        for (int l = 0; l < 2; ++l) {
            const int cr  = wave * 2 + l;
            const int loc = cr * 8 + r8;
            const int rho = h * 32 + (loc & 31) + ((loc >> 5) << 6);
            GLOAD_LDS(Bop + (size_t)rho * D_ + kt * 64 + srcc * 8, &Bs[c][h][cr * 8][0]);
        }
    };

    f32x4 acc[8][4] = {};
    bf16x8 ar[4][2], b0r[2][2], b1r[2][2];

    auto LDA = [&](int c, int mh) {
        #pragma unroll
        for (int i = 0; i < 4; ++i)
            #pragma unroll
            for (int kk = 0; kk < 2; ++kk)
                ar[i][kk] = *reinterpret_cast<const bf16x8*>(
                    &As[c][mh][wr * 64 + i * 16 + lr][(((kk * 4 + lg)) ^ (lr & 7)) * 8]);
    };
    auto LDB = [&](int c, int nh, bf16x8 (&br)[2][2]) {
        #pragma unroll
        for (int j = 0; j < 2; ++j)
            #pragma unroll
            for (int kk = 0; kk < 2; ++kk)
                br[j][kk] = *reinterpret_cast<const bf16x8*>(
                    &Bs[c][nh][wc * 32 + j * 16 + lr][(((kk * 4 + lg)) ^ (lr & 7)) * 8]);
    };
    auto QUAD = [&](const bf16x8 (&br)[2][2], int mh, int nh) {
        __builtin_amdgcn_s_setprio(1);
        #pragma unroll
        for (int i = 0; i < 4; ++i)
            #pragma unroll
            for (int j = 0; j < 2; ++j)
                #pragma unroll
                for (int kk = 0; kk < 2; ++kk)
                    acc[mh * 4 + i][nh * 2 + j] = __builtin_amdgcn_mfma_f32_16x16x32_bf16(
                        ar[i][kk], br[j][kk], acc[mh * 4 + i][nh * 2 + j], 0, 0, 0);
        __builtin_amdgcn_s_setprio(0);
    };

    constexpr int NK = D_ / 64;   // 16 K-tiles
    // prologue: tile0 all 4 halves + tile1's {A0, B1}
    stageA(0, 0, 0); stageB(0, 0, 0); stageA(0, 1, 0); stageB(0, 1, 0);
    stageA(1, 0, 1); stageB(1, 1, 1);
    asm volatile("s_waitcnt vmcnt(4)" ::: "memory");   // tile0 resident; t1's 2 stages in flight
    barrier_pin();

    #pragma unroll 1
    for (int t = 0; t < NK; ++t) {
        const int c = t & 1, cn = c ^ 1;
        const bool h1 = (t + 1 < NK), h2 = (t + 2 < NK);
        // ---- phase 0: quad (A0,B0); reads BEFORE barrier ----
        LDA(c, 0); LDB(c, 0, b0r);
        if (h1) stageA(cn, 1, t + 1);
        barrier_pin();
        QUAD(b0r, 0, 0);
        barrier_pin();
        // ---- phase 1: quad (A0,B1) ----
        LDB(c, 1, b1r);
        if (h1) stageB(cn, 0, t + 1);
        barrier_pin();
        QUAD(b1r, 0, 1);
        barrier_pin();
        // ---- phase 2: quad (A1,B1) ----
        LDA(c, 1);
        if (h2) stageA(c, 0, t + 2);     // A[c][0] dead since p0 (in regs)
        barrier_pin();
        QUAD(b1r, 1, 1);
        barrier_pin();
        // ---- phase 3: quad (A1,B0); B0 still in regs from p0 ----
        if (h2) stageB(c, 1, t + 2);     // B[c][1] dead since p1 (in regs)
        asm volatile("s_waitcnt vmcnt(4)" ::: "memory");   // tile t+1 fully resident
        barrier_pin();
        QUAD(b0r, 1, 0);
        barrier_pin();
    }

    // ---- epilogue ----
    if (mode == 0) {
        #pragma unroll
        for (int i = 0; i < 8; ++i)
            #pragma unroll
            for (int j = 0; j < 4; ++j)
                #pragma unroll
                for (int r = 0; r < 4; ++r) {
                    const int m  = mbase + wr * 128 + i * 16 + lg * 4 + r;   // token
                    const int nw = nbase + wc * 64 + j * 16 + lr;            // 0..1023
                    const float val = (acc[i][j][r] + bias[nw]) * scale;
                    const int b = m >> 11, tt = m & (T_ - 1);
                    const int h = nw >> 6, hd = nw & 63;
                    outp[((size_t)((b * H_ + h) * T_ + tt)) * HD_ + hd] = (bf16)val;
                }
    } else {
        #pragma unroll
        for (int i = 0; i < 8; ++i)
            #pragma unroll
            for (int j = 0; j < 4; ++j)
                #pragma unroll
                for (int r = 0; r < 4; ++r) {
                    const int d = mbase + wr * 128 + i * 16 + lg * 4 + r;    // 0..1023
                    const int n = nbase + wc * 64 + j * 16 + lr;             // token
                    const int b = n >> 11, tt = n & (T_ - 1);
                    outp[((size_t)(b * D_ + d)) * T_ + tt] = (bf16)(acc[i][j][r] + bias[d]);
                }
    }
}

// ========= out projection: BM=64 x BN=128 tiles, 512 blocks (2/CU), fp32 out =========
__global__ __launch_bounds__(256, 2) void gemm_out_kernel(
    const bf16* __restrict__ A, const bf16* __restrict__ WoT,
    const float* __restrict__ bo, float* __restrict__ Out)
{
    constexpr int K = D_;
    constexpr int NK = K / 64;
    __shared__ bf16 As[2][64][64];    // 16 KB
    __shared__ bf16 Bs[2][128][64];   // 32 KB

    const int bid = blockIdx.x;
    const int swz = (bid & 7) * 64 + (bid >> 3);   // XCD-bijective (512 % 8 == 0)
    const int m0 = (swz & 63) * 64, n0 = (swz >> 6) * 128;

    const int tid = threadIdx.x, wave = tid >> 6, lane = tid & 63;
    const int l5 = lane & 31, hi = lane >> 5;
    const int rseg = lane >> 3;
    const int srcc = (lane & 7) ^ rseg;

    auto stage = [&](int b, int k0) {
        #pragma unroll
        for (int cc = 0; cc < 2; ++cc) {       // A: 8 segs, 2/wave
            const int seg = wave * 2 + cc;
            const int row = seg * 8 + rseg;
            GLOAD_LDS(A + (size_t)(m0 + row) * K + k0 + srcc * 8, &As[b][seg * 8][0]);
        }
        #pragma unroll
        for (int cc = 0; cc < 4; ++cc) {       // B: 16 segs, 4/wave
            const int seg = wave * 4 + cc;
            const int row = seg * 8 + rseg;
            GLOAD_LDS(WoT + (size_t)(n0 + row) * K + k0 + srcc * 8, &Bs[b][seg * 8][0]);
        }
    };

    f32x16 acc[2] = {};
    stage(0, 0);
    __syncthreads();

    #pragma unroll 1
    for (int t = 0; t < NK; ++t) {
        const int cur = t & 1;
        if (t + 1 < NK) stage(cur ^ 1, (t + 1) * 64);

        bf16x8 af[2][4], bfr[4];
        #pragma unroll
        for (int mi = 0; mi < 2; ++mi)
            #pragma unroll
            for (int ks = 0; ks < 4; ++ks) {
                const int row = mi * 32 + l5;
                af[mi][ks] = *reinterpret_cast<const bf16x8*>(
                    &As[cur][row][((ks * 2 + hi) ^ (row & 7)) * 8]);
            }
        #pragma unroll
        for (int ks = 0; ks < 4; ++ks) {
            const int row = wave * 32 + l5;
            bfr[ks] = *reinterpret_cast<const bf16x8*>(
                &Bs[cur][row][((ks * 2 + hi) ^ (row & 7)) * 8]);
        }
        __builtin_amdgcn_s_setprio(1);
        #pragma unroll
        for (int mi = 0; mi < 2; ++mi)
            #pragma unroll
            for (int ks = 0; ks < 4; ++ks)
                acc[mi] = __builtin_amdgcn_mfma_f32_32x32x16_bf16(
                    af[mi][ks], bfr[ks], acc[mi], 0, 0, 0);
        __builtin_amdgcn_s_setprio(0);
        __syncthreads();
    }

    #pragma unroll
    for (int mi = 0; mi < 2; ++mi)
        #pragma unroll
        for (int q = 0; q < 16; ++q) {
            const int m = m0 + mi * 32 + (q & 3) + 8 * (q >> 2) + 4 * hi;
            const int n = n0 + wave * 32 + l5;
            Out[(size_t)m * D_ + n] = acc[mi][q] + bo[n];
        }
}

// ======= flash attention: QBLK=64, 4 waves, 512 paired blocks (2/CU), XCD-grouped =======
// Per-lane PARTIAL l_s (16 keys/lane); the cross-lane l reduce runs ONCE at the
// epilogue (butterfly gives all 4 row-lanes the total). Rescale alpha is row-uniform
// (m_s synced by the full row-max reduce inside the rare rescale branch).
__global__ __launch_bounds__(256) void attn_kernel(
    const bf16* __restrict__ Q, const bf16* __restrict__ K,
    const bf16* __restrict__ Vt, bf16* __restrict__ Out)
{
    const int bid = blockIdx.x;
    const int xcd = bid & 7, j = bid >> 3;       // j 0..63
    const int bh  = xcd * 4 + (j >> 4);          // 4 bh per XCD
    const int pr  = j & 15;                      // pair index 0..15

    const int tid = threadIdx.x, wave = tid >> 6, lane = tid & 63;  // 4 waves
    const int lr = lane & 15, lg = lane >> 4;
    const size_t kbase = (size_t)bh * T_ * HD_;   // Q,K
    const size_t vbase = (size_t)bh * HD_ * T_;   // Vt

    __shared__ bf16 Ks[2][64][64];   // 16 KB
    __shared__ bf16 Vs[2][64][64];   // 16 KB  (Vs[buf][d][key])
    __shared__ bf16 Ps[4][16][72];   // 9 KB   per-wave P[q][key], padded

    auto stage = [&](int sb, int kt) {
        const int kv0 = kt * 64;
        const int rseg = lane >> 3;
        const int srcw = (lane & 7) ^ rseg;      // XOR source-chunk swizzle (involution)
        #pragma unroll
        for (int cc = 0; cc < 2; ++cc) {
            const int seg = wave * 2 + cc;       // 0..7
            const int row = seg * 8 + rseg;      // 0..63
            GLOAD_LDS(K  + kbase + (size_t)(kv0 + row) * HD_ + srcw * 8, &Ks[sb][seg * 8][0]);
            GLOAD_LDS(Vt + vbase + (size_t)row * T_ + kv0 + srcw * 8,    &Vs[sb][seg * 8][0]);
        }
    };
    auto kfrag = [&](int sb, int row, int chunk) {
        return *reinterpret_cast<const bf16x8*>(&Ks[sb][row][(chunk ^ (row & 7)) * 8]);
    };
    auto vfrag = [&](int sb, int row, int chunk) {
        return *reinterpret_cast<const bf16x8*>(&Vs[sb][row][(chunk ^ (row & 7)) * 8]);
    };

    #pragma unroll 1
    for (int half = 0; half < 2; ++half) {
        const int qb = half == 0 ? pr : (NQB - 1 - pr);
        const int q0 = qb * 64;
        const int nt = qb + 1;                   // tiles 0..qb (all active)
        const int qw = wave * 16;

        // Q fragments for this wave's 16 rows (B-operand: col=lane&15 -> q=lr)
        bf16x8 qf[2];
        {
            const bf16* qrow = Q + kbase + (size_t)(q0 + qw + lr) * HD_;
            qf[0] = *reinterpret_cast<const bf16x8*>(qrow + lg * 8);
            qf[1] = *reinterpret_cast<const bf16x8*>(qrow + 32 + lg * 8);
        }

        float m_s = -1e30f, l_s = 0.f;           // m_s row-synced; l_s per-lane PARTIAL
        f32x4 o_acc[4] = {};                     // O[q=qw+lg*4+r][d=nd*16+lr]

        stage(0, 0);
        __syncthreads();

        #pragma unroll 1
        for (int t = 0; t < nt; ++t) {
            const int cur = t & 1;
            if (t + 1 < nt) stage(cur ^ 1, t + 1);   // prefetch next tile

            const int kv0 = t * 64;
            // S'[key][q]: key = kv0 + n16*16 + lg*4 + r, q = q0 + qw + lr
            f32x4 s[4] = {};
            __builtin_amdgcn_s_setprio(1);
            #pragma unroll
            for (int n16 = 0; n16 < 4; ++n16)
                #pragma unroll
                for (int kk = 0; kk < 2; ++kk)
                    s[n16] = __builtin_amdgcn_mfma_f32_16x16x32_bf16(
                        kfrag(cur, n16 * 16 + lr, kk * 4 + lg), qf[kk], s[n16], 0, 0, 0);
            __builtin_amdgcn_s_setprio(0);
            if (t == qb) {                       // causal mask on diagonal tile
                #pragma unroll
                for (int n16 = 0; n16 < 4; ++n16)
                    #pragma unroll
                    for (int r = 0; r < 4; ++r)
                        if (kv0 + n16 * 16 + lg * 4 + r > q0 + qw + lr)
                            s[n16][r] = -1e30f;
            }
            // online softmax, log2 domain, defer-max (8 nats = 11.54 bits)
            float mx = s[0][0];                  // lane-local 16-value max
            #pragma unroll
            for (int n16 = 0; n16 < 4; ++n16)
                #pragma unroll
                for (int r = 0; r < 4; ++r)
                    mx = fmaxf(mx, s[n16][r]);
            if (__any(mx > m_s + 11.5416f)) {    // rare: full row-max + rescale
                mx = fmaxf(mx, __shfl_xor(mx, 16));
                mx = fmaxf(mx, __shfl_xor(mx, 32));
                const float mnew  = fmaxf(m_s, mx);
                const float alpha = exp2_fast(m_s - mnew);   // row-uniform
                #pragma unroll
                for (int r = 0; r < 4; ++r) {
                    const float a = __shfl(alpha, lg * 4 + r);
                    #pragma unroll
                    for (int nd = 0; nd < 4; ++nd) o_acc[nd][r] *= a;
                }
                l_s *= alpha;                    // partial scaled consistently
                m_s = mnew;
            }
            #pragma unroll
            for (int n16 = 0; n16 < 4; ++n16) {
                bf16x4 pw;
                #pragma unroll
                for (int r = 0; r < 4; ++r) {
                    const float p = exp2_fast(s[n16][r] - m_s);   // bounded by 2^11.54
                    l_s += p;                    // per-lane partial, no shuffles
                    pw[r] = (bf16)p;
                }
                *reinterpret_cast<bf16x4*>(&Ps[wave][lr][n16 * 16 + lg * 4]) = pw;
            }
            // O += P @ V
            __builtin_amdgcn_s_setprio(1);
            #pragma unroll
            for (int ks = 0; ks < 2; ++ks) {
                const bf16x8 pa = *reinterpret_cast<const bf16x8*>(&Ps[wave][lr][ks * 32 + lg * 8]);
                #pragma unroll
                for (int nd = 0; nd < 4; ++nd)
                    o_acc[nd] = __builtin_amdgcn_mfma_f32_16x16x32_bf16(
                        pa, vfrag(cur, nd * 16 + lr, ks * 4 + lg), o_acc[nd], 0, 0, 0);
            }
            __builtin_amdgcn_s_setprio(0);
            __syncthreads();   // all reads of cur done; next tile fully staged
        }

        // final l reduce (once): butterfly over the 4 lanes sharing this row
        l_s += __shfl_xor(l_s, 16);
        l_s += __shfl_xor(l_s, 32);

        // normalize + store to [b*T+t][h*64+d]
        const int b = bh >> 4, h = bh & 15;
        const float linv = 1.0f / l_s;
        #pragma unroll
        for (int r = 0; r < 4; ++r) {
            const float li = __shfl(linv, lg * 4 + r);
            const int q = q0 + qw + lg * 4 + r;
            #pragma unroll
            for (int nd = 0; nd < 4; ++nd) {
                const int d = nd * 16 + lr;
                Out[((size_t)(b * T_ + q)) * D_ + h * HD_ + d] = (bf16)(o_acc[nd][r] * li);
            }
        }
    }
}

// ---------------- launch ----------------
extern "C" void kernel_launch(void* const* d_in, const int* in_sizes, int n_in,
                              void* d_out, int out_size, void* d_ws, size_t ws_size,
                              hipStream_t stream) {
    const float* x  = (const float*)d_in[0];
    const float* Wq = (const float*)d_in[1];
    const float* bq = (const float*)d_in[2];
    const float* Wk = (const float*)d_in[3];
    const float* bk = (const float*)d_in[4];
    const float* Wv = (const float*)d_in[5];
    const float* bv = (const float*)d_in[6];
    const float* Wo = (const float*)d_in[7];
    const float* bo = (const float*)d_in[8];
    float* out = (float*)d_out;

    char* ws = (char*)d_ws;
    bf16* xb   = (bf16*)(ws);                         // 8 MB  [4096][1024]
    bf16* WqT  = (bf16*)(ws + ( 8u << 20));           // 2 MB  [1024][1024]
    bf16* WkT  = (bf16*)(ws + (10u << 20));
    bf16* WvT  = (bf16*)(ws + (12u << 20));
    bf16* WoT  = (bf16*)(ws + (14u << 20));
    bf16* Qb   = (bf16*)(ws + (16u << 20));           // 8 MB  [32][2048][64]
    bf16* Kb   = (bf16*)(ws + (24u << 20));
    bf16* Vtb  = (bf16*)(ws + (32u << 20));           // 8 MB  [32][64][2048]
    bf16* attn = (bf16*)(ws + (40u << 20));           // 8 MB  [4096][1024]

    prep_kernel<<<dim3(32, 32, 5), 256, 0, stream>>>(
        x, xb, Wq, WqT, Wk, WkT, Wv, WvT, Wo, WoT);

    qkv256_kernel<<<192, 512, 0, stream>>>(xb, WqT, bq, Qb, WkT, bk, Kb, WvT, bv, Vtb);

    attn_kernel<<<512, 256, 0, stream>>>(Qb, Kb, Vtb, attn);

    gemm_out_kernel<<<512, 256, 0, stream>>>(attn, WoT, bo, out);
}